// Round 3
// baseline (244.226 us; speedup 1.0000x reference)
//
#include <hip/hip_runtime.h>
#include <hip/hip_bf16.h>

// ---------------------------------------------------------------------------
// TransformerPlanner: algebra-collapsed fused implementation.
//
// R3 changes vs R2 (k_main 76.5us, Occ 36%, ~112us fixed non-k_main overhead):
//  - k_tables + k_build MERGED into one k_prep (3 launches -> 2): token
//    block t computes its own v-projection column and writes OM cols h*20+t
//    directly; misc block writes OM cols 160..191.
//  - k_main: GEMM1 (P3) and fc2 (P6) are ROW-TILED (waves 0-2 own 16 output
//    rows x all 128 cols), making the 128-wide LN reductions wave-local
//    (4 shfl_xor) -- no Pp/mscA/Op LDS round trips. Barriers 12 -> 8.
//  - P2 softmax: 384 tasks spread over all 256 threads (pole 3 -> 2 tasks),
//    ra[] kept in LDS instead of regs (smaller live set, avoid spills).
//  - LDS 32256 -> 31872 (<=32KB) => 5 WGs/CU under __launch_bounds__(256,5).
// ---------------------------------------------------------------------------

typedef __bf16 bf16x8 __attribute__((ext_vector_type(8)));
typedef float  f32x4  __attribute__((ext_vector_type(4)));
static_assert(sizeof(bf16x8) == 16, "bf16x8 must be 16B");

__device__ __forceinline__ unsigned short f2b(float x) {
  __bf16 h = (__bf16)x;
  return __builtin_bit_cast(unsigned short, h);
}
__device__ __forceinline__ float b2f(unsigned short u) {
  return (float)__builtin_bit_cast(__bf16, u);
}
__device__ __forceinline__ float dot4(float4 a, float4 b) {
  return a.x*b.x + a.y*b.y + a.z*b.z + a.w*b.w;
}
__device__ __forceinline__ f32x4 mfma16(bf16x8 a, bf16x8 b, f32x4 c) {
  return __builtin_amdgcn_mfma_f32_16x16x32_bf16(a, b, c, 0, 0, 0);
}

// ---- workspace layout (byte offsets into d_ws) ----
#define WS_OM    0          // ushort[128*192]  combined attn GEMM weights (row n, K=192)
#define WS_FC1   49152      // ushort[256*128]  fc1 bf16 row-major (N,K)
#define WS_FC2   114688     // ushort[128*256]  fc2 bf16 row-major (N,K)
#define WS_QN    192000     // float[3*128]  LN'd queries
#define WS_SB    193536     // float[480]    Sb[w][h][t]
#define WS_SU    195456     // float[72]     Su[24],Sw[24],Sc[24]
#define WS_SCAL  195744     // float[3]      Suu,Sww,Suw
#define WS_SUB   195756     // float[20]
#define WS_SWB   195836     // float[20]
#define WS_SBB   195916     // float[20]

// ---------------------------------------------------------------------------
__device__ float mean128(float v, volatile float* red) {
  #pragma unroll
  for (int o = 32; o; o >>= 1) v += __shfl_down(v, o, 64);
  __syncthreads();
  if ((threadIdx.x & 63) == 0) red[threadIdx.x >> 6] = v;
  __syncthreads();
  return (red[0] + red[1]) * (1.0f / 128.0f);
}

// Merged prep kernel: 53 blocks x 128 threads.
//  b in [0,20)  : token block t -- per-t stats, Sb row, OM cols h*20+t
//  b == 20      : misc block -- scalars, QN, Su tables, OM cols 160..191
//  b in [21,37) : fc1 bf16 repack
//  b in [37,53) : fc2 bf16 repack
__global__ void k_prep(
    const float* __restrict__ coord_w, const float* __restrict__ coord_b,
    const float* __restrict__ pos_emb, const float* __restrict__ side_emb,
    const float* __restrict__ query_emb,
    const float* __restrict__ tln_g, const float* __restrict__ tln_b,
    const float* __restrict__ qln_g, const float* __restrict__ qln_b,
    const float* __restrict__ ipw, const float* __restrict__ ipb,
    const float* __restrict__ opw, const float* __restrict__ opb,
    const float* __restrict__ f1w, const float* __restrict__ f2w,
    char* __restrict__ ws)
{
  const int b = blockIdx.x, tid = threadIdx.x;   // 128 threads
  if (b >= 21) {
    if (b < 37) {
      unsigned short* dst = (unsigned short*)(ws + WS_FC1);
      int i0 = (b - 21)*2048;
      #pragma unroll
      for (int j = 0; j < 16; j++) { int i = i0 + j*128 + tid; dst[i] = f2b(f1w[i]); }
    } else {
      unsigned short* dst = (unsigned short*)(ws + WS_FC2);
      int i0 = (b - 37)*2048;
      #pragma unroll
      for (int j = 0; j < 16; j++) { int i = i0 + j*128 + tid; dst[i] = f2b(f2w[i]); }
    }
    return;
  }

  __shared__ float red[2];
  __shared__ float qn[3][128];
  __shared__ float qmat[3][128];
  __shared__ float vecA[128];
  __shared__ float vecB[128];
  __shared__ float vecC[128];
  __shared__ float kuA[128];
  __shared__ float kwA[128];
  __shared__ float kcA[128];
  const int d = tid;
  const int t = b;                // 0..19 = token blocks, 20 = misc

  float u  = coord_w[d*2+0];
  float w2 = coord_w[d*2+1];
  float g  = tln_g[d];
  float mu = mean128(u,  red);
  float mw = mean128(w2, red);
  float uh = u - mu, wh = w2 - mw;

  // LN(query_emb)
  #pragma unroll
  for (int w = 0; w < 3; w++) {
    float qe = query_emb[w*128 + d];
    float m  = mean128(qe, red);
    float m2 = mean128(qe*qe, red);
    float var = m2 - m*m;
    qn[w][d] = (qe - m) * rsqrtf(var + 1e-5f) * qln_g[d] + qln_b[d];
  }
  __syncthreads();
  // q = qn @ wq^T + bq
  {
    const float* wqr = ipw + d*128;
    float a0 = 0, a1 = 0, a2 = 0;
    for (int k4 = 0; k4 < 32; k4++) {
      float4 wv4 = *(const float4*)&wqr[k4*4];
      a0 += dot4(wv4, *(const float4*)&qn[0][k4*4]);
      a1 += dot4(wv4, *(const float4*)&qn[1][k4*4]);
      a2 += dot4(wv4, *(const float4*)&qn[2][k4*4]);
    }
    float bq = ipb[d];
    qmat[0][d] = a0 + bq; qmat[1][d] = a1 + bq; qmat[2][d] = a2 + bq;
  }
  __syncthreads();

  if (t < 20) {
    float base = coord_b[d] + pos_emb[(t % 10)*128 + d] + side_emb[(t < 10 ? 0 : 1)*128 + d];
    float mb = mean128(base, red);
    float bh = base - mb;
    float sub = mean128(uh*bh, red);
    float swb = mean128(wh*bh, red);
    float sbb = mean128(bh*bh, red);
    if (d == 0) {
      ((float*)(ws + WS_SUB))[t] = sub;
      ((float*)(ws + WS_SWB))[t] = swb;
      ((float*)(ws + WS_SBB))[t] = sbb;
    }
    vecA[d] = bh * g;
    __syncthreads();
    const float* wkr = ipw + (128 + d)*128;
    const float* wvr = ipw + (256 + d)*128;
    float kb = 0, vb = 0;
    for (int k4 = 0; k4 < 32; k4++) {
      float4 a4 = *(const float4*)&vecA[k4*4];
      kb += dot4(*(const float4*)&wkr[k4*4], a4);
      vb += dot4(*(const float4*)&wvr[k4*4], a4);
    }
    kuA[d] = kb;
    vecB[d] = vb;
    __syncthreads();
    if (d < 24) {
      int w = d / 8, h = d % 8;
      float s = 0;
      #pragma unroll
      for (int dl = 0; dl < 16; dl++) s += qmat[w][h*16 + dl] * kuA[h*16 + dl];
      ((float*)(ws + WS_SB))[(w*8 + h)*20 + t] = 0.25f * s;
    }
    // OM columns h*20+t for every output row n = d
    {
      const float* opr = opw + d*128;
      float acc[8] = {0,0,0,0,0,0,0,0};
      #pragma unroll
      for (int k4 = 0; k4 < 32; k4++) {
        float4 o4 = *(const float4*)&opr[k4*4];
        acc[k4 >> 2] += dot4(o4, *(const float4*)&vecB[k4*4]);
      }
      unsigned short* OMr = (unsigned short*)(ws + WS_OM) + d*192;
      #pragma unroll
      for (int h = 0; h < 8; h++) OMr[h*20 + t] = f2b(acc[h]);
    }
  } else {
    float suu = mean128(uh*uh, red);
    float sww = mean128(wh*wh, red);
    float suw = mean128(uh*wh, red);
    if (d == 0) {
      float* sc = (float*)(ws + WS_SCAL);
      sc[0] = suu; sc[1] = sww; sc[2] = suw;
    }
    vecA[d] = uh * g; vecB[d] = wh * g; vecC[d] = tln_b[d];
    __syncthreads();
    const float* wkr = ipw + (128 + d)*128;
    const float* wvr = ipw + (256 + d)*128;
    float ku = 0, kw = 0, kc = 0, vu = 0, vw = 0, vc = 0;
    for (int k4 = 0; k4 < 32; k4++) {
      float4 a4 = *(const float4*)&vecA[k4*4];
      float4 b4 = *(const float4*)&vecB[k4*4];
      float4 c4 = *(const float4*)&vecC[k4*4];
      float4 kv = *(const float4*)&wkr[k4*4];
      float4 vv = *(const float4*)&wvr[k4*4];
      ku += dot4(kv, a4); kw += dot4(kv, b4); kc += dot4(kv, c4);
      vu += dot4(vv, a4); vw += dot4(vv, b4); vc += dot4(vv, c4);
    }
    kc += ipb[128 + d]; vc += ipb[256 + d];
    kuA[d] = ku; kwA[d] = kw; kcA[d] = kc;
    float* qnw = (float*)(ws + WS_QN);
    qnw[0*128 + d] = qn[0][d]; qnw[1*128 + d] = qn[1][d]; qnw[2*128 + d] = qn[2][d];
    __syncthreads();
    // repurpose vecA/B/C to hold vu/vw/vc (all proj reads are done)
    vecA[d] = vu; vecB[d] = vw; vecC[d] = vc;
    __syncthreads();
    if (d < 24) {
      int w = d / 8, h = d % 8;
      float su = 0, sw = 0, sc2 = 0;
      #pragma unroll
      for (int dl = 0; dl < 16; dl++) {
        float q = qmat[w][h*16 + dl];
        su  += q * kuA[h*16 + dl];
        sw  += q * kwA[h*16 + dl];
        sc2 += q * kcA[h*16 + dl];
      }
      float* o = (float*)(ws + WS_SU);
      o[ 0 + w*8 + h] = 0.25f * su;
      o[24 + w*8 + h] = 0.25f * sw;
      o[48 + w*8 + h] = 0.25f * sc2;
    }
    // OM columns 160..191 for every output row n = d
    {
      const float* opr = opw + d*128;
      float au[8] = {0,0,0,0,0,0,0,0};
      float aw[8] = {0,0,0,0,0,0,0,0};
      float ac = 0;
      #pragma unroll
      for (int k4 = 0; k4 < 32; k4++) {
        float4 o4 = *(const float4*)&opr[k4*4];
        au[k4 >> 2] += dot4(o4, *(const float4*)&vecA[k4*4]);
        aw[k4 >> 2] += dot4(o4, *(const float4*)&vecB[k4*4]);
        ac          += dot4(o4, *(const float4*)&vecC[k4*4]);
      }
      unsigned short* OMr = (unsigned short*)(ws + WS_OM) + d*192;
      #pragma unroll
      for (int h = 0; h < 8; h++) {
        OMr[160 + h] = f2b(au[h]);
        OMr[168 + h] = f2b(aw[h]);
      }
      OMr[176] = f2b(ac + opb[d]);
      #pragma unroll
      for (int i = 177; i < 192; i++) OMr[i] = 0;
    }
  }
}

// ---------------------------------------------------------------------------
// Main fused kernel: 16 batch elements per WG (M = 48 rows), 256 threads.
// LDS 31872 B (<=32KB) -> 5 WGs/CU.
//
// LDS regions / liveness:
//  A [0,19200)      : Z 48x200 bf16 (P0-P3 reads); X 48x132 bf16 aliases
//                     [0,12672) after barrier b4 (all Z reads done).
//  B [19200,31872)  : P0-P3: xr/yr/rsA/Sbl/SulA/QNl/pagl/pabl (8608 B);
//                     FFN: h1 48x132 bf16 (12672 B) overlays everything
//                     after b5.
// Barriers: b1(P0) b2(P1) b3(P2) b4(Z-dead) b5(X-ready)
//           b6(h1 half0 ready) b7(h1 half0 reads done) b8(h1 half1 ready).
#define GE 16
#define MR 48
#define SMEM_SZ 31872

__global__ __launch_bounds__(256, 5) void k_main(
    const float* __restrict__ tl, const float* __restrict__ tr,
    const float* __restrict__ f1b, const float* __restrict__ f2b_,
    const float* __restrict__ pag, const float* __restrict__ pab,
    const float* __restrict__ pfg, const float* __restrict__ pfb,
    const float* __restrict__ hw, const float* __restrict__ hb,
    const char* __restrict__ ws, float* __restrict__ out)
{
  __shared__ __align__(16) char smem[SMEM_SZ];
  // region A
  unsigned short* Z  = (unsigned short*)(smem);          // 48x200 (P0-P3)
  unsigned short* X  = (unsigned short*)(smem);          // 48x132 (aliases Z, post-b4)
  // region B
  float* xr   = (float*)(smem + 19200);                  // 16x20
  float* yr   = (float*)(smem + 20480);
  float* rsA  = (float*)(smem + 21760);
  float* Sbl  = (float*)(smem + 23040);                  // 480
  float* SulA = (float*)(smem + 24960);                  // 72 (Su,Sw,Sc)
  float* QNl  = (float*)(smem + 25248);                  // 3x128
  float* pagl = (float*)(smem + 26784);                  // 128
  float* pabl = (float*)(smem + 27296);                  // 128
  unsigned short* h1 = (unsigned short*)(smem + 19200);  // 48x132 (FFN halves)

  const unsigned short* OM = (const unsigned short*)(ws + WS_OM);
  const unsigned short* W1 = (const unsigned short*)(ws + WS_FC1);
  const unsigned short* W2 = (const unsigned short*)(ws + WS_FC2);
  const float* QNw  = (const float*)(ws + WS_QN);
  const float* SBw  = (const float*)(ws + WS_SB);
  const float* SUw  = (const float*)(ws + WS_SU);
  const float* SCAL = (const float*)(ws + WS_SCAL);
  const float* SUB  = (const float*)(ws + WS_SUB);
  const float* SWB  = (const float*)(ws + WS_SWB);
  const float* SBB  = (const float*)(ws + WS_SBB);

  const int tid  = threadIdx.x;
  const int wg   = blockIdx.x;
  const int lane = tid & 63;
  const int wv   = tid >> 6;
  const int c    = lane & 15;     // MFMA col-in-tile / A-row index
  const int g    = lane >> 4;     // MFMA k-slice / output row-group

  // ---- P0: stage tables, init Z constant tail, load coords ----
  for (int i = tid; i < 480; i += 256) Sbl[i] = SBw[i];
  if (tid < 72) SulA[tid] = SUw[tid];
  if (tid < 128) {
    QNl[tid] = QNw[tid]; QNl[128 + tid] = QNw[128 + tid]; QNl[256 + tid] = QNw[256 + tid];
    pagl[tid] = pag[tid]; pabl[tid] = pab[tid];
  }
  if (tid < 48) {
    unsigned short* Zr = Z + tid*200;
    Zr[176] = 0x3F80;                  // bf16 1.0
    #pragma unroll
    for (int i = 177; i < 192; i++) Zr[i] = 0;
  }
  if (tid < 160) {
    int half = tid / 80;               // 0 = left, 1 = right
    int i4   = tid % 80;
    const float* src = half ? tr : tl;
    float4 v = *(const float4*)(src + wg*(GE*20) + i4*4);
    int e  = i4 / 5;
    int j  = (i4 % 5) * 4;
    int t0 = half*10 + j/2;
    xr[e*20 + t0]     = v.x; yr[e*20 + t0]     = v.y;
    xr[e*20 + t0 + 1] = v.z; yr[e*20 + t0 + 1] = v.w;
  }
  __syncthreads();                                        // b1

  // ---- P1: rs_t = rsqrt(quadratic(x,y) + eps); xr,yr <- x*rs, y*rs ----
  {
    float suu = SCAL[0], sww = SCAL[1], suw = SCAL[2];
    for (int i = tid; i < GE*20; i += 256) {
      int t = i % 20;
      float x = xr[i], y = yr[i];
      float var = suu*x*x + sww*y*y + 2.0f*suw*x*y
                + 2.0f*SUB[t]*x + 2.0f*SWB[t]*y + SBB[t];
      float rv = rsqrtf(var + 1e-5f);
      rsA[i] = rv; xr[i] = x*rv; yr[i] = y*rv;
    }
  }
  __syncthreads();                                        // b2

  // ---- P2: scores + softmax + P,Q -> Z rows (bf16) ----
  // 384 (e,h,w) tasks over 256 threads: tid<128 -> w=0 and w=2; else w=1.
  {
    const int e = tid & 15;
    const int h = (tid >> 4) & 7;
    float xa[20], ya[20];
    #pragma unroll
    for (int tb = 0; tb < 5; tb++) {
      float4 xv = *(const float4*)&xr[e*20 + tb*4];
      float4 yv = *(const float4*)&yr[e*20 + tb*4];
      xa[tb*4+0]=xv.x; xa[tb*4+1]=xv.y; xa[tb*4+2]=xv.z; xa[tb*4+3]=xv.w;
      ya[tb*4+0]=yv.x; ya[tb*4+1]=yv.y; ya[tb*4+2]=yv.z; ya[tb*4+3]=yv.w;
    }
    const int ntask = (tid < 128) ? 2 : 1;
    const int wfirst = (tid < 128) ? 0 : 1;
    for (int it = 0; it < ntask; it++) {
      int w = (it == 0) ? wfirst : 2;
      float suv = SulA[w*8 + h], swv = SulA[24 + w*8 + h], scv = SulA[48 + w*8 + h];
      const float* sb = &Sbl[(w*8 + h)*20];
      float s[20];
      #pragma unroll
      for (int tb = 0; tb < 5; tb++) {
        float4 s4 = *(const float4*)&sb[tb*4];
        float4 rv = *(const float4*)&rsA[e*20 + tb*4];
        s[tb*4+0] = fmaf(xa[tb*4+0],suv, fmaf(ya[tb*4+0],swv, fmaf(rv.x,s4.x, scv)));
        s[tb*4+1] = fmaf(xa[tb*4+1],suv, fmaf(ya[tb*4+1],swv, fmaf(rv.y,s4.y, scv)));
        s[tb*4+2] = fmaf(xa[tb*4+2],suv, fmaf(ya[tb*4+2],swv, fmaf(rv.z,s4.z, scv)));
        s[tb*4+3] = fmaf(xa[tb*4+3],suv, fmaf(ya[tb*4+3],swv, fmaf(rv.w,s4.w, scv)));
      }
      float m = s[0];
      #pragma unroll
      for (int t2 = 1; t2 < 20; t2++) m = fmaxf(m, s[t2]);
      float sum = 0;
      #pragma unroll
      for (int t2 = 0; t2 < 20; t2++) { float p = __expf(s[t2] - m); s[t2] = p; sum += p; }
      float inv = 1.0f / sum;
      float P = 0, Q = 0;
      #pragma unroll
      for (int t2 = 0; t2 < 20; t2++) { P = fmaf(s[t2], xa[t2], P); Q = fmaf(s[t2], ya[t2], Q); }
      P *= inv; Q *= inv;
      unsigned short* Zr = Z + (e*3 + w)*200;
      #pragma unroll
      for (int t2 = 0; t2 < 10; t2++) {
        unsigned int lo = f2b(s[2*t2]   * rsA[e*20 + 2*t2]   * inv);
        unsigned int hi = f2b(s[2*t2+1] * rsA[e*20 + 2*t2+1] * inv);
        *(unsigned int*)&Zr[h*20 + 2*t2] = lo | (hi << 16);
      }
      Zr[160 + h] = f2b(P);
      Zr[168 + h] = f2b(Q);
    }
  }
  __syncthreads();                                        // b3

  // ---- P3: GEMM1 row-tiled (waves 0-2 own 16 rows x 128 cols) + wave-local LN ----
  f32x4 acc[8];
  float m3[4], sc3[4];
  if (wv < 3) {
    #pragma unroll
    for (int nt = 0; nt < 8; nt++) acc[nt] = (f32x4){0.f,0.f,0.f,0.f};
    #pragma unroll
    for (int kt = 0; kt < 6; kt++) {
      bf16x8 Af = *(const bf16x8*)(Z + (wv*16 + c)*200 + kt*32 + g*8);
      #pragma unroll
      for (int nt = 0; nt < 8; nt++) {
        bf16x8 Bf = *(const bf16x8*)(OM + (nt*16 + c)*192 + kt*32 + g*8);
        acc[nt] = mfma16(Af, Bf, acc[nt]);
      }
    }
    // add queries_n; row mean/var fully within this wave (shfl over c-group)
    #pragma unroll
    for (int j = 0; j < 4; j++) {
      int row = wv*16 + g*4 + j;
      const float* qrow = &QNl[(row % 3) * 128];
      float s1 = 0.f, s2 = 0.f;
      #pragma unroll
      for (int nt = 0; nt < 8; nt++) {
        float v = acc[nt][j] + qrow[nt*16 + c];
        acc[nt][j] = v;
        s1 += v; s2 += v*v;
      }
      s1 += __shfl_xor(s1, 1); s1 += __shfl_xor(s1, 2);
      s1 += __shfl_xor(s1, 4); s1 += __shfl_xor(s1, 8);
      s2 += __shfl_xor(s2, 1); s2 += __shfl_xor(s2, 2);
      s2 += __shfl_xor(s2, 4); s2 += __shfl_xor(s2, 8);
      float m = s1 * (1.0f/128.0f);
      m3[j]  = m;
      sc3[j] = rsqrtf(s2 * (1.0f/128.0f) - m*m + 1e-5f);
    }
  }
  __syncthreads();                                        // b4: all Z reads done
  if (wv < 3) {
    #pragma unroll
    for (int nt = 0; nt < 8; nt++) {
      int col = nt*16 + c;
      float pg = pagl[col], pb = pabl[col];
      #pragma unroll
      for (int j = 0; j < 4; j++) {
        int row = wv*16 + g*4 + j;
        X[row*132 + col] = f2b((acc[nt][j] - m3[j])*sc3[j]*pg + pb);
      }
    }
  }
  __syncthreads();                                        // b5: X ready, region B free

  // ---- FFN: two K=128 halves; fc1 N-split (4 waves), fc2 row-tiled (waves 0-2) ----
  f32x4 acc2[8];
  #pragma unroll
  for (int nt = 0; nt < 8; nt++) acc2[nt] = (f32x4){0.f,0.f,0.f,0.f};

  #pragma unroll
  for (int hh = 0; hh < 2; hh++) {
    // fc1 half hh -> relu -> h1 (cols 32*wv..+32 of this half)
    {
      f32x4 a1[3][2];
      #pragma unroll
      for (int mt = 0; mt < 3; mt++)
        #pragma unroll
        for (int nt = 0; nt < 2; nt++) a1[mt][nt] = (f32x4){0.f,0.f,0.f,0.f};
      #pragma unroll
      for (int kt = 0; kt < 4; kt++) {
        bf16x8 Af[3];
        #pragma unroll
        for (int mt = 0; mt < 3; mt++)
          Af[mt] = *(const bf16x8*)(X + (mt*16 + c)*132 + kt*32 + g*8);
        #pragma unroll
        for (int nt = 0; nt < 2; nt++) {
          int n = hh*128 + wv*32 + nt*16 + c;
          bf16x8 Bf = *(const bf16x8*)(W1 + n*128 + kt*32 + g*8);
          a1[0][nt] = mfma16(Af[0], Bf, a1[0][nt]);
          a1[1][nt] = mfma16(Af[1], Bf, a1[1][nt]);
          a1[2][nt] = mfma16(Af[2], Bf, a1[2][nt]);
        }
      }
      #pragma unroll
      for (int nt = 0; nt < 2; nt++) {
        int lcol = wv*32 + nt*16 + c;
        float bb = f1b[hh*128 + lcol];
        #pragma unroll
        for (int mt = 0; mt < 3; mt++)
          #pragma unroll
          for (int j = 0; j < 4; j++)
            h1[(mt*16 + g*4 + j)*132 + lcol] = f2b(fmaxf(a1[mt][nt][j] + bb, 0.0f));
      }
    }
    __syncthreads();                                      // b6 / b8: h1 ready
    // fc2 partial over this half (row-tiled), accumulate into acc2
    if (wv < 3) {
      #pragma unroll
      for (int kt = 0; kt < 4; kt++) {
        bf16x8 Af = *(const bf16x8*)(h1 + (wv*16 + c)*132 + kt*32 + g*8);
        #pragma unroll
        for (int nt = 0; nt < 8; nt++) {
          bf16x8 Bf = *(const bf16x8*)(W2 + (nt*16 + c)*256 + hh*128 + kt*32 + g*8);
          acc2[nt] = mfma16(Af, Bf, acc2[nt]);
        }
      }
    }
    if (hh == 0) __syncthreads();                         // b7: h1 reads done
  }

  // ---- Epilogue: h2+bias+residual -> wave-local LN -> head -> out ----
  if (wv < 3) {
    #pragma unroll
    for (int j = 0; j < 4; j++) {
      int row = wv*16 + g*4 + j;
      float s1 = 0.f, s2 = 0.f;
      #pragma unroll
      for (int nt = 0; nt < 8; nt++) {
        int col = nt*16 + c;
        float v = acc2[nt][j] + f2b_[col] + b2f(X[row*132 + col]);
        acc2[nt][j] = v;
        s1 += v; s2 += v*v;
      }
      s1 += __shfl_xor(s1, 1); s1 += __shfl_xor(s1, 2);
      s1 += __shfl_xor(s1, 4); s1 += __shfl_xor(s1, 8);
      s2 += __shfl_xor(s2, 1); s2 += __shfl_xor(s2, 2);
      s2 += __shfl_xor(s2, 4); s2 += __shfl_xor(s2, 8);
      float m  = s1 * (1.0f/128.0f);
      float sc = rsqrtf(s2 * (1.0f/128.0f) - m*m + 1e-5f);
      float o0 = 0.f, o1 = 0.f;
      #pragma unroll
      for (int nt = 0; nt < 8; nt++) {
        int col = nt*16 + c;
        float xl = (acc2[nt][j] - m)*sc*pfg[col] + pfb[col];
        o0 = fmaf(xl, hw[col],       o0);
        o1 = fmaf(xl, hw[128 + col], o1);
      }
      o0 += __shfl_xor(o0, 1); o0 += __shfl_xor(o0, 2);
      o0 += __shfl_xor(o0, 4); o0 += __shfl_xor(o0, 8);
      o1 += __shfl_xor(o1, 1); o1 += __shfl_xor(o1, 2);
      o1 += __shfl_xor(o1, 4); o1 += __shfl_xor(o1, 8);
      if (c == 0) {
        int gr = wg*48 + row;
        *(float2*)&out[gr*2] = make_float2(o0 + hb[0], o1 + hb[1]);
      }
    }
  }
}

// ---------------------------------------------------------------------------
extern "C" void kernel_launch(void* const* d_in, const int* in_sizes, int n_in,
                              void* d_out, int out_size, void* d_ws, size_t ws_size,
                              hipStream_t stream) {
  const float* tl       = (const float*)d_in[0];
  const float* tr       = (const float*)d_in[1];
  const float* coord_w  = (const float*)d_in[2];
  const float* coord_b  = (const float*)d_in[3];
  const float* pos_emb  = (const float*)d_in[4];
  const float* side_emb = (const float*)d_in[5];
  const float* query_emb= (const float*)d_in[6];
  const float* tln_g    = (const float*)d_in[7];
  const float* tln_b    = (const float*)d_in[8];
  const float* qln_g    = (const float*)d_in[9];
  const float* qln_b    = (const float*)d_in[10];
  const float* ipw      = (const float*)d_in[11];
  const float* ipb      = (const float*)d_in[12];
  const float* opw      = (const float*)d_in[13];
  const float* opb      = (const float*)d_in[14];
  const float* f1w      = (const float*)d_in[15];
  const float* f1b      = (const float*)d_in[16];
  const float* f2w      = (const float*)d_in[17];
  const float* f2b2     = (const float*)d_in[18];
  const float* pag      = (const float*)d_in[19];
  const float* pab      = (const float*)d_in[20];
  const float* pfg      = (const float*)d_in[21];
  const float* pfb      = (const float*)d_in[22];
  const float* hw       = (const float*)d_in[23];
  const float* hb       = (const float*)d_in[24];
  char* ws = (char*)d_ws;

  k_prep<<<53, 128, 0, stream>>>(coord_w, coord_b, pos_emb, side_emb, query_emb,
                                 tln_g, tln_b, qln_g, qln_b, ipw, ipb,
                                 opw, opb, f1w, f2w, ws);
  k_main<<<32768 / GE, 256, 0, stream>>>(tl, tr, f1b, f2b2, pag, pab, pfg, pfb,
                                         hw, hb, ws, (float*)d_out);
}

// Round 4
// 192.723 us; speedup vs baseline: 1.2672x; 1.2672x over previous
//
#include <hip/hip_runtime.h>
#include <hip/hip_bf16.h>

// ---------------------------------------------------------------------------
// TransformerPlanner: algebra-collapsed fused implementation.
//
// R4: REVERT to R2's k_main structure (proven 76.5us; R3's row-tiling
// re-streamed B-fragments from L2 inside the MFMA loop => regression).
// Single change vs R2: __launch_bounds__(256,3) instead of (256,4).
// Evidence: R1 at (256,3) had VGPR=76, WRITE_SIZE=768KB (clean);
// R2/R3 at (256,4)/(256,5) had VGPR=64/48, WRITE_SIZE~10-11MB (scratch
// spills of P2's s[20]/xa[20]/ya[20] live set). Let the allocator breathe.
// k_prep (merged tables+build, 2 launches) retained from R3 -- neutral.
// ---------------------------------------------------------------------------

typedef __bf16 bf16x8 __attribute__((ext_vector_type(8)));
typedef float  f32x4  __attribute__((ext_vector_type(4)));
static_assert(sizeof(bf16x8) == 16, "bf16x8 must be 16B");

__device__ __forceinline__ unsigned short f2b(float x) {
  __bf16 h = (__bf16)x;
  return __builtin_bit_cast(unsigned short, h);
}
__device__ __forceinline__ float b2f(unsigned short u) {
  return (float)__builtin_bit_cast(__bf16, u);
}
__device__ __forceinline__ float dot4(float4 a, float4 b) {
  return a.x*b.x + a.y*b.y + a.z*b.z + a.w*b.w;
}
__device__ __forceinline__ f32x4 mfma16(bf16x8 a, bf16x8 b, f32x4 c) {
  return __builtin_amdgcn_mfma_f32_16x16x32_bf16(a, b, c, 0, 0, 0);
}

// ---- workspace layout (byte offsets into d_ws) ----
#define WS_OM    0          // ushort[128*192]  combined attn GEMM weights (row n, K=192)
#define WS_FC1   49152      // ushort[256*128]  fc1 bf16 row-major (N,K)
#define WS_FC2   114688     // ushort[128*256]  fc2 bf16 row-major (N,K)
#define WS_QN    192000     // float[3*128]  LN'd queries
#define WS_SB    193536     // float[480]    Sb[w][h][t]
#define WS_SU    195456     // float[72]     Su[24],Sw[24],Sc[24]
#define WS_SCAL  195744     // float[3]      Suu,Sww,Suw
#define WS_SUB   195756     // float[20]
#define WS_SWB   195836     // float[20]
#define WS_SBB   195916     // float[20]

// ---------------------------------------------------------------------------
__device__ float mean128(float v, volatile float* red) {
  #pragma unroll
  for (int o = 32; o; o >>= 1) v += __shfl_down(v, o, 64);
  __syncthreads();
  if ((threadIdx.x & 63) == 0) red[threadIdx.x >> 6] = v;
  __syncthreads();
  return (red[0] + red[1]) * (1.0f / 128.0f);
}

// Merged prep kernel: 53 blocks x 128 threads.
//  b in [0,20)  : token block t -- per-t stats, Sb row, OM cols h*20+t
//  b == 20      : misc block -- scalars, QN, Su tables, OM cols 160..191
//  b in [21,37) : fc1 bf16 repack
//  b in [37,53) : fc2 bf16 repack
__global__ void k_prep(
    const float* __restrict__ coord_w, const float* __restrict__ coord_b,
    const float* __restrict__ pos_emb, const float* __restrict__ side_emb,
    const float* __restrict__ query_emb,
    const float* __restrict__ tln_g, const float* __restrict__ tln_b,
    const float* __restrict__ qln_g, const float* __restrict__ qln_b,
    const float* __restrict__ ipw, const float* __restrict__ ipb,
    const float* __restrict__ opw, const float* __restrict__ opb,
    const float* __restrict__ f1w, const float* __restrict__ f2w,
    char* __restrict__ ws)
{
  const int b = blockIdx.x, tid = threadIdx.x;   // 128 threads
  if (b >= 21) {
    if (b < 37) {
      unsigned short* dst = (unsigned short*)(ws + WS_FC1);
      int i0 = (b - 21)*2048;
      #pragma unroll
      for (int j = 0; j < 16; j++) { int i = i0 + j*128 + tid; dst[i] = f2b(f1w[i]); }
    } else {
      unsigned short* dst = (unsigned short*)(ws + WS_FC2);
      int i0 = (b - 37)*2048;
      #pragma unroll
      for (int j = 0; j < 16; j++) { int i = i0 + j*128 + tid; dst[i] = f2b(f2w[i]); }
    }
    return;
  }

  __shared__ float red[2];
  __shared__ float qn[3][128];
  __shared__ float qmat[3][128];
  __shared__ float vecA[128];
  __shared__ float vecB[128];
  __shared__ float vecC[128];
  __shared__ float kuA[128];
  __shared__ float kwA[128];
  __shared__ float kcA[128];
  const int d = tid;
  const int t = b;                // 0..19 = token blocks, 20 = misc

  float u  = coord_w[d*2+0];
  float w2 = coord_w[d*2+1];
  float g  = tln_g[d];
  float mu = mean128(u,  red);
  float mw = mean128(w2, red);
  float uh = u - mu, wh = w2 - mw;

  // LN(query_emb)
  #pragma unroll
  for (int w = 0; w < 3; w++) {
    float qe = query_emb[w*128 + d];
    float m  = mean128(qe, red);
    float m2 = mean128(qe*qe, red);
    float var = m2 - m*m;
    qn[w][d] = (qe - m) * rsqrtf(var + 1e-5f) * qln_g[d] + qln_b[d];
  }
  __syncthreads();
  // q = qn @ wq^T + bq
  {
    const float* wqr = ipw + d*128;
    float a0 = 0, a1 = 0, a2 = 0;
    for (int k4 = 0; k4 < 32; k4++) {
      float4 wv4 = *(const float4*)&wqr[k4*4];
      a0 += dot4(wv4, *(const float4*)&qn[0][k4*4]);
      a1 += dot4(wv4, *(const float4*)&qn[1][k4*4]);
      a2 += dot4(wv4, *(const float4*)&qn[2][k4*4]);
    }
    float bq = ipb[d];
    qmat[0][d] = a0 + bq; qmat[1][d] = a1 + bq; qmat[2][d] = a2 + bq;
  }
  __syncthreads();

  if (t < 20) {
    float base = coord_b[d] + pos_emb[(t % 10)*128 + d] + side_emb[(t < 10 ? 0 : 1)*128 + d];
    float mb = mean128(base, red);
    float bh = base - mb;
    float sub = mean128(uh*bh, red);
    float swb = mean128(wh*bh, red);
    float sbb = mean128(bh*bh, red);
    if (d == 0) {
      ((float*)(ws + WS_SUB))[t] = sub;
      ((float*)(ws + WS_SWB))[t] = swb;
      ((float*)(ws + WS_SBB))[t] = sbb;
    }
    vecA[d] = bh * g;
    __syncthreads();
    const float* wkr = ipw + (128 + d)*128;
    const float* wvr = ipw + (256 + d)*128;
    float kb = 0, vb = 0;
    for (int k4 = 0; k4 < 32; k4++) {
      float4 a4 = *(const float4*)&vecA[k4*4];
      kb += dot4(*(const float4*)&wkr[k4*4], a4);
      vb += dot4(*(const float4*)&wvr[k4*4], a4);
    }
    kuA[d] = kb;
    vecB[d] = vb;
    __syncthreads();
    if (d < 24) {
      int w = d / 8, h = d % 8;
      float s = 0;
      #pragma unroll
      for (int dl = 0; dl < 16; dl++) s += qmat[w][h*16 + dl] * kuA[h*16 + dl];
      ((float*)(ws + WS_SB))[(w*8 + h)*20 + t] = 0.25f * s;
    }
    // OM columns h*20+t for every output row n = d
    {
      const float* opr = opw + d*128;
      float acc[8] = {0,0,0,0,0,0,0,0};
      #pragma unroll
      for (int k4 = 0; k4 < 32; k4++) {
        float4 o4 = *(const float4*)&opr[k4*4];
        acc[k4 >> 2] += dot4(o4, *(const float4*)&vecB[k4*4]);
      }
      unsigned short* OMr = (unsigned short*)(ws + WS_OM) + d*192;
      #pragma unroll
      for (int h = 0; h < 8; h++) OMr[h*20 + t] = f2b(acc[h]);
    }
  } else {
    float suu = mean128(uh*uh, red);
    float sww = mean128(wh*wh, red);
    float suw = mean128(uh*wh, red);
    if (d == 0) {
      float* sc = (float*)(ws + WS_SCAL);
      sc[0] = suu; sc[1] = sww; sc[2] = suw;
    }
    vecA[d] = uh * g; vecB[d] = wh * g; vecC[d] = tln_b[d];
    __syncthreads();
    const float* wkr = ipw + (128 + d)*128;
    const float* wvr = ipw + (256 + d)*128;
    float ku = 0, kw = 0, kc = 0, vu = 0, vw = 0, vc = 0;
    for (int k4 = 0; k4 < 32; k4++) {
      float4 a4 = *(const float4*)&vecA[k4*4];
      float4 b4 = *(const float4*)&vecB[k4*4];
      float4 c4 = *(const float4*)&vecC[k4*4];
      float4 kv = *(const float4*)&wkr[k4*4];
      float4 vv = *(const float4*)&wvr[k4*4];
      ku += dot4(kv, a4); kw += dot4(kv, b4); kc += dot4(kv, c4);
      vu += dot4(vv, a4); vw += dot4(vv, b4); vc += dot4(vv, c4);
    }
    kc += ipb[128 + d]; vc += ipb[256 + d];
    kuA[d] = ku; kwA[d] = kw; kcA[d] = kc;
    float* qnw = (float*)(ws + WS_QN);
    qnw[0*128 + d] = qn[0][d]; qnw[1*128 + d] = qn[1][d]; qnw[2*128 + d] = qn[2][d];
    __syncthreads();
    // repurpose vecA/B/C to hold vu/vw/vc (all proj reads are done)
    vecA[d] = vu; vecB[d] = vw; vecC[d] = vc;
    __syncthreads();
    if (d < 24) {
      int w = d / 8, h = d % 8;
      float su = 0, sw = 0, sc2 = 0;
      #pragma unroll
      for (int dl = 0; dl < 16; dl++) {
        float q = qmat[w][h*16 + dl];
        su  += q * kuA[h*16 + dl];
        sw  += q * kwA[h*16 + dl];
        sc2 += q * kcA[h*16 + dl];
      }
      float* o = (float*)(ws + WS_SU);
      o[ 0 + w*8 + h] = 0.25f * su;
      o[24 + w*8 + h] = 0.25f * sw;
      o[48 + w*8 + h] = 0.25f * sc2;
    }
    // OM columns 160..191 for every output row n = d
    {
      const float* opr = opw + d*128;
      float au[8] = {0,0,0,0,0,0,0,0};
      float aw[8] = {0,0,0,0,0,0,0,0};
      float ac = 0;
      #pragma unroll
      for (int k4 = 0; k4 < 32; k4++) {
        float4 o4 = *(const float4*)&opr[k4*4];
        au[k4 >> 2] += dot4(o4, *(const float4*)&vecA[k4*4]);
        aw[k4 >> 2] += dot4(o4, *(const float4*)&vecB[k4*4]);
        ac          += dot4(o4, *(const float4*)&vecC[k4*4]);
      }
      unsigned short* OMr = (unsigned short*)(ws + WS_OM) + d*192;
      #pragma unroll
      for (int h = 0; h < 8; h++) {
        OMr[160 + h] = f2b(au[h]);
        OMr[168 + h] = f2b(aw[h]);
      }
      OMr[176] = f2b(ac + opb[d]);
      #pragma unroll
      for (int i = 177; i < 192; i++) OMr[i] = 0;
    }
  }
}

// ---------------------------------------------------------------------------
// Main fused kernel: 16 batch elements per WG (M = 48 rows), 256 threads.
// LDS 32256 B; __launch_bounds__(256,3) -> ~170 VGPR cap, no spills.
//
// LDS regions / liveness:
//  A [0,19200)     : Z 48x200 bf16 (P0-P3 reads) ; X 48x136 bf16 aliases
//                    [0,13056) after b4; [13056,16512) hosts Pp2/msc2/Op.
//  B [19200,32256) : P0-P3: xr/yr/rsA/Sbl/SulA/QNl/pagl/pabl/Pp/mscA;
//                    P5/P6: h1 half-buffer 48x136 bf16 (both K-halves).
#define GE 16
#define MR 48
#define SMEM_SZ 32256

__global__ __launch_bounds__(256, 3) void k_main(
    const float* __restrict__ tl, const float* __restrict__ tr,
    const float* __restrict__ f1b, const float* __restrict__ f2b_,
    const float* __restrict__ pag, const float* __restrict__ pab,
    const float* __restrict__ pfg, const float* __restrict__ pfb,
    const float* __restrict__ hw, const float* __restrict__ hb,
    const char* __restrict__ ws, float* __restrict__ out)
{
  __shared__ __align__(16) char smem[SMEM_SZ];
  // region A
  unsigned short* Z  = (unsigned short*)(smem);          // 48x200 (P0-P3)
  unsigned short* X  = (unsigned short*)(smem);          // 48x136 (aliases Z, post-b4)
  float* Pp2  = (float*)(smem + 13056);                  // [48][4] float2
  float* msc2 = (float*)(smem + 14592);                  // [48] float2
  float* Op   = (float*)(smem + 14976);                  // [48][4] float2
  // region B
  float* xr   = (float*)(smem + 19200);                  // 16x20
  float* yr   = (float*)(smem + 20480);
  float* rsA  = (float*)(smem + 21760);
  float* Sbl  = (float*)(smem + 23040);                  // 480
  float* SulA = (float*)(smem + 24960);                  // 72 (Su,Sw,Sc)
  float* QNl  = (float*)(smem + 25248);                  // 3x128
  float* pagl = (float*)(smem + 26784);                  // 128
  float* pabl = (float*)(smem + 27296);                  // 128
  float* Pp   = (float*)(smem + 27808);                  // [48][4] float2
  float* mscA = (float*)(smem + 29344);                  // [48] float2
  unsigned short* h1 = (unsigned short*)(smem + 19200);  // 48x136 (P5/P6)

  const unsigned short* OM = (const unsigned short*)(ws + WS_OM);
  const unsigned short* W1 = (const unsigned short*)(ws + WS_FC1);
  const unsigned short* W2 = (const unsigned short*)(ws + WS_FC2);
  const float* QNw  = (const float*)(ws + WS_QN);
  const float* SBw  = (const float*)(ws + WS_SB);
  const float* SUw  = (const float*)(ws + WS_SU);
  const float* SCAL = (const float*)(ws + WS_SCAL);
  const float* SUB  = (const float*)(ws + WS_SUB);
  const float* SWB  = (const float*)(ws + WS_SWB);
  const float* SBB  = (const float*)(ws + WS_SBB);

  const int tid  = threadIdx.x;
  const int wg   = blockIdx.x;
  const int lane = tid & 63;
  const int wv   = tid >> 6;
  const int c    = lane & 15;     // MFMA column-in-tile / A-row index
  const int g    = lane >> 4;     // MFMA k-slice / output row-group
  const int nb   = wv * 32;       // N-slice base for this wave

  // ---- P0: stage tables, init Z constant tail, load coords ----
  for (int i = tid; i < 480; i += 256) Sbl[i] = SBw[i];
  if (tid < 72) SulA[tid] = SUw[tid];
  for (int i = tid; i < 384; i += 256) QNl[i] = QNw[i];
  if (tid < 128) { pagl[tid] = pag[tid]; pabl[tid] = pab[tid]; }
  if (tid < 48) {
    unsigned short* Zr = Z + tid*200;
    Zr[176] = 0x3F80;                  // bf16 1.0
    #pragma unroll
    for (int i = 177; i < 192; i++) Zr[i] = 0;
  }
  if (tid < 160) {
    int half = tid / 80;               // 0 = left, 1 = right
    int i4   = tid % 80;
    const float* src = half ? tr : tl;
    float4 v = *(const float4*)(src + wg*(GE*20) + i4*4);
    int e  = i4 / 5;
    int j  = (i4 % 5) * 4;
    int t0 = half*10 + j/2;
    xr[e*20 + t0]     = v.x; yr[e*20 + t0]     = v.y;
    xr[e*20 + t0 + 1] = v.z; yr[e*20 + t0 + 1] = v.w;
  }
  __syncthreads();                                        // b1

  // ---- P1: rs_t = rsqrt(quadratic(x,y) + eps); xr,yr <- x*rs, y*rs ----
  {
    float suu = SCAL[0], sww = SCAL[1], suw = SCAL[2];
    for (int i = tid; i < GE*20; i += 256) {
      int t = i % 20;
      float x = xr[i], y = yr[i];
      float var = suu*x*x + sww*y*y + 2.0f*suw*x*y
                + 2.0f*SUB[t]*x + 2.0f*SWB[t]*y + SBB[t];
      float rv = rsqrtf(var + 1e-5f);
      rsA[i] = rv; xr[i] = x*rv; yr[i] = y*rv;
    }
  }
  __syncthreads();                                        // b2

  // ---- P2: scores + softmax + P,Q -> Z rows (bf16) ----
  if (tid < 128) {
    int e = tid >> 3, h = tid & 7;
    float xa[20], ya[20], ra[20];
    #pragma unroll
    for (int tb = 0; tb < 5; tb++) {
      float4 xv = *(const float4*)&xr[e*20 + tb*4];
      float4 yv = *(const float4*)&yr[e*20 + tb*4];
      float4 rv = *(const float4*)&rsA[e*20 + tb*4];
      xa[tb*4+0]=xv.x; xa[tb*4+1]=xv.y; xa[tb*4+2]=xv.z; xa[tb*4+3]=xv.w;
      ya[tb*4+0]=yv.x; ya[tb*4+1]=yv.y; ya[tb*4+2]=yv.z; ya[tb*4+3]=yv.w;
      ra[tb*4+0]=rv.x; ra[tb*4+1]=rv.y; ra[tb*4+2]=rv.z; ra[tb*4+3]=rv.w;
    }
    float s[3][20];
    #pragma unroll
    for (int w = 0; w < 3; w++) {
      float suv = SulA[w*8 + h], swv = SulA[24 + w*8 + h], scv = SulA[48 + w*8 + h];
      const float* sb = &Sbl[(w*8 + h)*20];
      #pragma unroll
      for (int tb = 0; tb < 5; tb++) {
        float4 s4 = *(const float4*)&sb[tb*4];
        s[w][tb*4+0] = fmaf(xa[tb*4+0],suv, fmaf(ya[tb*4+0],swv, fmaf(ra[tb*4+0],s4.x, scv)));
        s[w][tb*4+1] = fmaf(xa[tb*4+1],suv, fmaf(ya[tb*4+1],swv, fmaf(ra[tb*4+1],s4.y, scv)));
        s[w][tb*4+2] = fmaf(xa[tb*4+2],suv, fmaf(ya[tb*4+2],swv, fmaf(ra[tb*4+2],s4.z, scv)));
        s[w][tb*4+3] = fmaf(xa[tb*4+3],suv, fmaf(ya[tb*4+3],swv, fmaf(ra[tb*4+3],s4.w, scv)));
      }
    }
    unsigned short* Zr0 = Z + e*3*200;
    #pragma unroll
    for (int w = 0; w < 3; w++) {
      float m = s[w][0];
      #pragma unroll
      for (int t2 = 1; t2 < 20; t2++) m = fmaxf(m, s[w][t2]);
      float sum = 0;
      #pragma unroll
      for (int t2 = 0; t2 < 20; t2++) { float p = __expf(s[w][t2] - m); s[w][t2] = p; sum += p; }
      float inv = 1.0f / sum;
      float P = 0, Q = 0;
      #pragma unroll
      for (int t2 = 0; t2 < 20; t2++) { P = fmaf(s[w][t2], xa[t2], P); Q = fmaf(s[w][t2], ya[t2], Q); }
      P *= inv; Q *= inv;
      unsigned short* Zr = Zr0 + w*200;
      #pragma unroll
      for (int t2 = 0; t2 < 10; t2++) {
        unsigned int lo = f2b(s[w][2*t2]   * ra[2*t2]   * inv);
        unsigned int hi = f2b(s[w][2*t2+1] * ra[2*t2+1] * inv);
        *(unsigned int*)&Zr[h*20 + 2*t2] = lo | (hi << 16);
      }
      Zr[160 + h] = f2b(P);
      Zr[168 + h] = f2b(Q);
    }
  }
  __syncthreads();                                        // b3

  // ---- P3: GEMM1 attn_out = Z(48x192) @ OM^T, fused LN -> X bf16 ----
  {
    bf16x8 Bf[2][6];
    #pragma unroll
    for (int nt = 0; nt < 2; nt++)
      #pragma unroll
      for (int kt = 0; kt < 6; kt++)
        Bf[nt][kt] = *(const bf16x8*)(OM + (nb + nt*16 + c)*192 + kt*32 + g*8);
    f32x4 acc[3][2];
    #pragma unroll
    for (int mt = 0; mt < 3; mt++)
      #pragma unroll
      for (int nt = 0; nt < 2; nt++) acc[mt][nt] = (f32x4){0.f,0.f,0.f,0.f};
    #pragma unroll
    for (int kt = 0; kt < 6; kt++) {
      bf16x8 Af[3];
      #pragma unroll
      for (int mt = 0; mt < 3; mt++)
        Af[mt] = *(const bf16x8*)(Z + (mt*16 + c)*200 + kt*32 + g*8);
      #pragma unroll
      for (int mt = 0; mt < 3; mt++)
        #pragma unroll
        for (int nt = 0; nt < 2; nt++)
          acc[mt][nt] = mfma16(Af[mt], Bf[nt][kt], acc[mt][nt]);
    }
    // fragment-LN: add queries_n, column-group reduce for mean/var
    float p1[3][4], p2[3][4];
    #pragma unroll
    for (int mt = 0; mt < 3; mt++)
      #pragma unroll
      for (int j = 0; j < 4; j++) {
        int row = mt*16 + g*4 + j;
        int w = row % 3;
        float v0 = acc[mt][0][j] + QNl[w*128 + nb + c];
        float v1 = acc[mt][1][j] + QNl[w*128 + nb + 16 + c];
        acc[mt][0][j] = v0; acc[mt][1][j] = v1;
        p1[mt][j] = v0 + v1;
        p2[mt][j] = v0*v0 + v1*v1;
      }
    #pragma unroll
    for (int mt = 0; mt < 3; mt++)
      #pragma unroll
      for (int j = 0; j < 4; j++) {
        #pragma unroll
        for (int mk = 1; mk <= 8; mk <<= 1) {
          p1[mt][j] += __shfl_xor(p1[mt][j], mk, 64);
          p2[mt][j] += __shfl_xor(p2[mt][j], mk, 64);
        }
      }
    if (c < 4) {
      #pragma unroll
      for (int mt = 0; mt < 3; mt++) {
        float a = (c==0)?p1[mt][0]:(c==1)?p1[mt][1]:(c==2)?p1[mt][2]:p1[mt][3];
        float b = (c==0)?p2[mt][0]:(c==1)?p2[mt][1]:(c==2)?p2[mt][2]:p2[mt][3];
        int row = mt*16 + g*4 + c;
        *(float2*)&Pp[row*8 + wv*2] = make_float2(a, b);
      }
    }
    __syncthreads();                                      // b4 (also: all Z reads done)
    if (tid < 192) {
      int row = tid >> 2, q = tid & 3;
      float2 pp = *(const float2*)&Pp[row*8 + q*2];
      float s1v = pp.x, s2v = pp.y;
      s1v += __shfl_xor(s1v, 1, 64); s1v += __shfl_xor(s1v, 2, 64);
      s2v += __shfl_xor(s2v, 1, 64); s2v += __shfl_xor(s2v, 2, 64);
      if (q == 0) {
        float m = s1v * (1.0f/128.0f);
        float var = s2v * (1.0f/128.0f) - m*m;
        *(float2*)&mscA[row*2] = make_float2(m, rsqrtf(var + 1e-5f));
      }
    }
    __syncthreads();                                      // b5
    // X = LN'd x, written straight from fragments (X aliases dead Z)
    {
      float pg0 = pagl[nb + c],      pb0 = pabl[nb + c];
      float pg1 = pagl[nb + 16 + c], pb1 = pabl[nb + 16 + c];
      #pragma unroll
      for (int mt = 0; mt < 3; mt++)
        #pragma unroll
        for (int j = 0; j < 4; j++) {
          int row = mt*16 + g*4 + j;
          float2 ms = *(const float2*)&mscA[row*2];
          X[row*136 + nb + c]      = f2b((acc[mt][0][j] - ms.x)*ms.y*pg0 + pb0);
          X[row*136 + nb + 16 + c] = f2b((acc[mt][1][j] - ms.x)*ms.y*pg1 + pb1);
        }
    }
  }
  __syncthreads();                                        // b6

  // ---- P5/P6: FFN in two K=128 halves sharing h1 (48x136 bf16) ----
  f32x4 acc2[3][2];
  #pragma unroll
  for (int mt = 0; mt < 3; mt++)
    #pragma unroll
    for (int nt = 0; nt < 2; nt++) acc2[mt][nt] = (f32x4){0.f,0.f,0.f,0.f};

  #pragma unroll
  for (int h = 0; h < 2; h++) {
    // P5: fc1 half -> relu -> h1
    {
      bf16x8 Bf[2][4];
      #pragma unroll
      for (int nt = 0; nt < 2; nt++)
        #pragma unroll
        for (int kt = 0; kt < 4; kt++)
          Bf[nt][kt] = *(const bf16x8*)(W1 + (h*128 + nb + nt*16 + c)*128 + kt*32 + g*8);
      f32x4 acc[3][2];
      #pragma unroll
      for (int mt = 0; mt < 3; mt++)
        #pragma unroll
        for (int nt = 0; nt < 2; nt++) acc[mt][nt] = (f32x4){0.f,0.f,0.f,0.f};
      #pragma unroll
      for (int kt = 0; kt < 4; kt++) {
        bf16x8 Af[3];
        #pragma unroll
        for (int mt = 0; mt < 3; mt++)
          Af[mt] = *(const bf16x8*)(X + (mt*16 + c)*136 + kt*32 + g*8);
        #pragma unroll
        for (int mt = 0; mt < 3; mt++)
          #pragma unroll
          for (int nt = 0; nt < 2; nt++)
            acc[mt][nt] = mfma16(Af[mt], Bf[nt][kt], acc[mt][nt]);
      }
      float bb0 = f1b[h*128 + nb + c];
      float bb1 = f1b[h*128 + nb + 16 + c];
      #pragma unroll
      for (int mt = 0; mt < 3; mt++)
        #pragma unroll
        for (int j = 0; j < 4; j++) {
          int row = mt*16 + g*4 + j;
          h1[row*136 + nb + c]      = f2b(fmaxf(acc[mt][0][j] + bb0, 0.0f));
          h1[row*136 + nb + 16 + c] = f2b(fmaxf(acc[mt][1][j] + bb1, 0.0f));
        }
    }
    __syncthreads();                                      // b7 / b9
    // P6: fc2 partial over this K-half, accumulate into acc2
    {
      bf16x8 Bf[2][4];
      #pragma unroll
      for (int nt = 0; nt < 2; nt++)
        #pragma unroll
        for (int kt = 0; kt < 4; kt++)
          Bf[nt][kt] = *(const bf16x8*)(W2 + (nb + nt*16 + c)*256 + h*128 + kt*32 + g*8);
      #pragma unroll
      for (int kt = 0; kt < 4; kt++) {
        bf16x8 Af[3];
        #pragma unroll
        for (int mt = 0; mt < 3; mt++)
          Af[mt] = *(const bf16x8*)(h1 + (mt*16 + c)*136 + kt*32 + g*8);
        #pragma unroll
        for (int mt = 0; mt < 3; mt++)
          #pragma unroll
          for (int nt = 0; nt < 2; nt++)
            acc2[mt][nt] = mfma16(Af[mt], Bf[nt][kt], acc2[mt][nt]);
      }
    }
    if (h == 0) __syncthreads();                          // b8 (h1 rewrite guard)
  }

  // ---- P6b epilogue: h2+bias+residual -> fragment-LN -> head -> out ----
  {
    float bb0 = f2b_[nb + c];
    float bb1 = f2b_[nb + 16 + c];
    float p1[3][4], p2[3][4];
    #pragma unroll
    for (int mt = 0; mt < 3; mt++)
      #pragma unroll
      for (int j = 0; j < 4; j++) {
        int row = mt*16 + g*4 + j;
        float v0 = acc2[mt][0][j] + bb0 + b2f(X[row*136 + nb + c]);
        float v1 = acc2[mt][1][j] + bb1 + b2f(X[row*136 + nb + 16 + c]);
        acc2[mt][0][j] = v0; acc2[mt][1][j] = v1;
        p1[mt][j] = v0 + v1;
        p2[mt][j] = v0*v0 + v1*v1;
      }
    #pragma unroll
    for (int mt = 0; mt < 3; mt++)
      #pragma unroll
      for (int j = 0; j < 4; j++) {
        #pragma unroll
        for (int mk = 1; mk <= 8; mk <<= 1) {
          p1[mt][j] += __shfl_xor(p1[mt][j], mk, 64);
          p2[mt][j] += __shfl_xor(p2[mt][j], mk, 64);
        }
      }
    if (c < 4) {
      #pragma unroll
      for (int mt = 0; mt < 3; mt++) {
        float a = (c==0)?p1[mt][0]:(c==1)?p1[mt][1]:(c==2)?p1[mt][2]:p1[mt][3];
        float b = (c==0)?p2[mt][0]:(c==1)?p2[mt][1]:(c==2)?p2[mt][2]:p2[mt][3];
        int row = mt*16 + g*4 + c;
        *(float2*)&Pp2[row*8 + wv*2] = make_float2(a, b);
      }
    }
    __syncthreads();                                      // b10
    if (tid < 192) {
      int row = tid >> 2, q = tid & 3;
      float2 pp = *(const float2*)&Pp2[row*8 + q*2];
      float s1v = pp.x, s2v = pp.y;
      s1v += __shfl_xor(s1v, 1, 64); s1v += __shfl_xor(s1v, 2, 64);
      s2v += __shfl_xor(s2v, 1, 64); s2v += __shfl_xor(s2v, 2, 64);
      if (q == 0) {
        float m = s1v * (1.0f/128.0f);
        float var = s2v * (1.0f/128.0f) - m*m;
        *(float2*)&msc2[row*2] = make_float2(m, rsqrtf(var + 1e-5f));
      }
    }
    __syncthreads();                                      // b11
    {
      float fg0 = pfg[nb + c],        fb0 = pfb[nb + c];
      float fg1 = pfg[nb + 16 + c],   fb1 = pfb[nb + 16 + c];
      float hw00 = hw[nb + c],        hw01 = hw[nb + 16 + c];
      float hw10 = hw[128 + nb + c],  hw11 = hw[128 + nb + 16 + c];
      float o0[3][4], o1[3][4];
      #pragma unroll
      for (int mt = 0; mt < 3; mt++)
        #pragma unroll
        for (int j = 0; j < 4; j++) {
          int row = mt*16 + g*4 + j;
          float2 ms = *(const float2*)&msc2[row*2];
          float x0 = (acc2[mt][0][j] - ms.x)*ms.y*fg0 + fb0;
          float x1 = (acc2[mt][1][j] - ms.x)*ms.y*fg1 + fb1;
          o0[mt][j] = x0*hw00 + x1*hw01;
          o1[mt][j] = x0*hw10 + x1*hw11;
        }
      #pragma unroll
      for (int mt = 0; mt < 3; mt++)
        #pragma unroll
        for (int j = 0; j < 4; j++) {
          #pragma unroll
          for (int mk = 1; mk <= 8; mk <<= 1) {
            o0[mt][j] += __shfl_xor(o0[mt][j], mk, 64);
            o1[mt][j] += __shfl_xor(o1[mt][j], mk, 64);
          }
        }
      if (c < 4) {
        #pragma unroll
        for (int mt = 0; mt < 3; mt++) {
          float a = (c==0)?o0[mt][0]:(c==1)?o0[mt][1]:(c==2)?o0[mt][2]:o0[mt][3];
          float b = (c==0)?o1[mt][0]:(c==1)?o1[mt][1]:(c==2)?o1[mt][2]:o1[mt][3];
          int row = mt*16 + g*4 + c;
          *(float2*)&Op[row*8 + wv*2] = make_float2(a, b);
        }
      }
    }
    __syncthreads();                                      // b12
    if (tid < 48) {
      float4 a = *(const float4*)&Op[tid*8];
      float4 b = *(const float4*)&Op[tid*8 + 4];
      out[(wg*48 + tid)*2]     = a.x + a.z + b.x + b.z + hb[0];
      out[(wg*48 + tid)*2 + 1] = a.y + a.w + b.y + b.w + hb[1];
    }
  }
}

// ---------------------------------------------------------------------------
extern "C" void kernel_launch(void* const* d_in, const int* in_sizes, int n_in,
                              void* d_out, int out_size, void* d_ws, size_t ws_size,
                              hipStream_t stream) {
  const float* tl       = (const float*)d_in[0];
  const float* tr       = (const float*)d_in[1];
  const float* coord_w  = (const float*)d_in[2];
  const float* coord_b  = (const float*)d_in[3];
  const float* pos_emb  = (const float*)d_in[4];
  const float* side_emb = (const float*)d_in[5];
  const float* query_emb= (const float*)d_in[6];
  const float* tln_g    = (const float*)d_in[7];
  const float* tln_b    = (const float*)d_in[8];
  const float* qln_g    = (const float*)d_in[9];
  const float* qln_b    = (const float*)d_in[10];
  const float* ipw      = (const float*)d_in[11];
  const float* ipb      = (const float*)d_in[12];
  const float* opw      = (const float*)d_in[13];
  const float* opb      = (const float*)d_in[14];
  const float* f1w      = (const float*)d_in[15];
  const float* f1b      = (const float*)d_in[16];
  const float* f2w      = (const float*)d_in[17];
  const float* f2b2     = (const float*)d_in[18];
  const float* pag      = (const float*)d_in[19];
  const float* pab      = (const float*)d_in[20];
  const float* pfg      = (const float*)d_in[21];
  const float* pfb      = (const float*)d_in[22];
  const float* hw       = (const float*)d_in[23];
  const float* hb       = (const float*)d_in[24];
  char* ws = (char*)d_ws;

  k_prep<<<53, 128, 0, stream>>>(coord_w, coord_b, pos_emb, side_emb, query_emb,
                                 tln_g, tln_b, qln_g, qln_b, ipw, ipb,
                                 opw, opb, f1w, f2w, ws);
  k_main<<<32768 / GE, 256, 0, stream>>>(tl, tr, f1b, f2b2, pag, pab, pfg, pfb,
                                         hw, hb, ws, (float*)d_out);
}

// Round 7
// 173.668 us; speedup vs baseline: 1.4063x; 1.1097x over previous
//
#include <hip/hip_runtime.h>
#include <hip/hip_bf16.h>

// ---------------------------------------------------------------------------
// TransformerPlanner: algebra-collapsed fused implementation.
//
// R7: bisection round. k_main = R4's proven structure/arithmetic (12-barrier,
// P1+P2 separate, two-stage LN reduce, non-atomic epilogue) at R2's measured
// best __launch_bounds__(256,4). Carried from R5/R6 ONLY the two
// arithmetic-neutral mechanisms:
//  (a) OM/W1/W2 stored in MFMA-fragment order (k_prep) -> each wave's B-load
//      is one coalesced 1KB line (was 16B/lane x 384B-stride).
//  (b) Cross-barrier prefetch of B fragments (OM before the Z barrier,
//      W1h0 during X-write, W2 before h1-ready barrier, W1h1 before b8).
// R5/R6's P1-merge + per-thread m/sc + atomicAdd epilogue are REVERTED
// (one of them holds the 0.12-absmax bug; isolate later if worth it).
// ---------------------------------------------------------------------------

typedef __bf16 bf16x8 __attribute__((ext_vector_type(8)));
typedef float  f32x4  __attribute__((ext_vector_type(4)));
static_assert(sizeof(bf16x8) == 16, "bf16x8 must be 16B");

__device__ __forceinline__ unsigned short f2b(float x) {
  __bf16 h = (__bf16)x;
  return __builtin_bit_cast(unsigned short, h);
}
__device__ __forceinline__ float b2f(unsigned short u) {
  return (float)__builtin_bit_cast(__bf16, u);
}
__device__ __forceinline__ float dot4(float4 a, float4 b) {
  return a.x*b.x + a.y*b.y + a.z*b.z + a.w*b.w;
}
__device__ __forceinline__ f32x4 mfma16(bf16x8 a, bf16x8 b, f32x4 c) {
  return __builtin_amdgcn_mfma_f32_16x16x32_bf16(a, b, c, 0, 0, 0);
}

// Fragment-order offsets (ushort index) for B matrices:
// lane l of a (ntile,ktile) block holds n = ntile*16 + (l&15),
// k = ktile*32 + (l>>4)*8 .. +8. Block = 64 lanes x 8 ushort = 512.
__device__ __forceinline__ int om_off(int n, int k) {   // 128x192, 6 ktiles
  return (((n >> 4)*6 + (k >> 5))*64 + ((k >> 3) & 3)*16 + (n & 15))*8 + (k & 7);
}
__device__ __forceinline__ int w1_off(int n, int k) {   // 256x128, 4 ktiles
  return (((n >> 4)*4 + (k >> 5))*64 + ((k >> 3) & 3)*16 + (n & 15))*8 + (k & 7);
}
__device__ __forceinline__ int w2_off(int n, int k) {   // 128x256, 8 ktiles
  return (((n >> 4)*8 + (k >> 5))*64 + ((k >> 3) & 3)*16 + (n & 15))*8 + (k & 7);
}

// ---- workspace layout (byte offsets into d_ws) ----
#define WS_OM    0          // ushort[24576]  OM fragments (8 ntile x 6 ktile)
#define WS_FC1   49152      // ushort[32768]  fc1 fragments (16 x 4)
#define WS_FC2   114688     // ushort[32768]  fc2 fragments (8 x 8)
#define WS_QN    192000     // float[3*128]  LN'd queries
#define WS_SB    193536     // float[480]    Sb[w][h][t]
#define WS_SU    195456     // float[72]     Su[24],Sw[24],Sc[24]
#define WS_SCAL  195744     // float[3]      Suu,Sww,Suw
#define WS_SUB   195756     // float[20]
#define WS_SWB   195836     // float[20]
#define WS_SBB   195916     // float[20]

// ---------------------------------------------------------------------------
__device__ float mean128(float v, volatile float* red) {
  #pragma unroll
  for (int o = 32; o; o >>= 1) v += __shfl_down(v, o, 64);
  __syncthreads();
  if ((threadIdx.x & 63) == 0) red[threadIdx.x >> 6] = v;
  __syncthreads();
  return (red[0] + red[1]) * (1.0f / 128.0f);
}

// Merged prep kernel: 53 blocks x 128 threads.
//  b in [0,20)  : token block t -- per-t stats, Sb row, OM cols h*20+t
//  b == 20      : misc block -- scalars, QN, Su tables, OM cols 160..191
//  b in [21,37) : fc1 bf16 fragment repack
//  b in [37,53) : fc2 bf16 fragment repack
__global__ void k_prep(
    const float* __restrict__ coord_w, const float* __restrict__ coord_b,
    const float* __restrict__ pos_emb, const float* __restrict__ side_emb,
    const float* __restrict__ query_emb,
    const float* __restrict__ tln_g, const float* __restrict__ tln_b,
    const float* __restrict__ qln_g, const float* __restrict__ qln_b,
    const float* __restrict__ ipw, const float* __restrict__ ipb,
    const float* __restrict__ opw, const float* __restrict__ opb,
    const float* __restrict__ f1w, const float* __restrict__ f2w,
    char* __restrict__ ws)
{
  const int b = blockIdx.x, tid = threadIdx.x;   // 128 threads
  if (b >= 21) {
    if (b < 37) {
      unsigned short* dst = (unsigned short*)(ws + WS_FC1);
      int i0 = (b - 21)*2048;
      #pragma unroll
      for (int j = 0; j < 16; j++) {
        int i = i0 + j*128 + tid;
        dst[w1_off(i >> 7, i & 127)] = f2b(f1w[i]);
      }
    } else {
      unsigned short* dst = (unsigned short*)(ws + WS_FC2);
      int i0 = (b - 37)*2048;
      #pragma unroll
      for (int j = 0; j < 16; j++) {
        int i = i0 + j*128 + tid;
        dst[w2_off(i >> 8, i & 255)] = f2b(f2w[i]);
      }
    }
    return;
  }

  __shared__ float red[2];
  __shared__ float qn[3][128];
  __shared__ float qmat[3][128];
  __shared__ float vecA[128];
  __shared__ float vecB[128];
  __shared__ float vecC[128];
  __shared__ float kuA[128];
  __shared__ float kwA[128];
  __shared__ float kcA[128];
  const int d = tid;
  const int t = b;                // 0..19 = token blocks, 20 = misc
  unsigned short* OMw = (unsigned short*)(ws + WS_OM);

  float u  = coord_w[d*2+0];
  float w2 = coord_w[d*2+1];
  float g  = tln_g[d];
  float mu = mean128(u,  red);
  float mw = mean128(w2, red);
  float uh = u - mu, wh = w2 - mw;

  // LN(query_emb)
  #pragma unroll
  for (int w = 0; w < 3; w++) {
    float qe = query_emb[w*128 + d];
    float m  = mean128(qe, red);
    float m2 = mean128(qe*qe, red);
    float var = m2 - m*m;
    qn[w][d] = (qe - m) * rsqrtf(var + 1e-5f) * qln_g[d] + qln_b[d];
  }
  __syncthreads();
  // q = qn @ wq^T + bq
  {
    const float* wqr = ipw + d*128;
    float a0 = 0, a1 = 0, a2 = 0;
    for (int k4 = 0; k4 < 32; k4++) {
      float4 wv4 = *(const float4*)&wqr[k4*4];
      a0 += dot4(wv4, *(const float4*)&qn[0][k4*4]);
      a1 += dot4(wv4, *(const float4*)&qn[1][k4*4]);
      a2 += dot4(wv4, *(const float4*)&qn[2][k4*4]);
    }
    float bq = ipb[d];
    qmat[0][d] = a0 + bq; qmat[1][d] = a1 + bq; qmat[2][d] = a2 + bq;
  }
  __syncthreads();

  if (t < 20) {
    float base = coord_b[d] + pos_emb[(t % 10)*128 + d] + side_emb[(t < 10 ? 0 : 1)*128 + d];
    float mb = mean128(base, red);
    float bh = base - mb;
    float sub = mean128(uh*bh, red);
    float swb = mean128(wh*bh, red);
    float sbb = mean128(bh*bh, red);
    if (d == 0) {
      ((float*)(ws + WS_SUB))[t] = sub;
      ((float*)(ws + WS_SWB))[t] = swb;
      ((float*)(ws + WS_SBB))[t] = sbb;
    }
    vecA[d] = bh * g;
    __syncthreads();
    const float* wkr = ipw + (128 + d)*128;
    const float* wvr = ipw + (256 + d)*128;
    float kb = 0, vb = 0;
    for (int k4 = 0; k4 < 32; k4++) {
      float4 a4 = *(const float4*)&vecA[k4*4];
      kb += dot4(*(const float4*)&wkr[k4*4], a4);
      vb += dot4(*(const float4*)&wvr[k4*4], a4);
    }
    kuA[d] = kb;
    vecB[d] = vb;
    __syncthreads();
    if (d < 24) {
      int w = d / 8, h = d % 8;
      float s = 0;
      #pragma unroll
      for (int dl = 0; dl < 16; dl++) s += qmat[w][h*16 + dl] * kuA[h*16 + dl];
      ((float*)(ws + WS_SB))[(w*8 + h)*20 + t] = 0.25f * s;
    }
    // OM columns h*20+t for every output row n = d (fragment layout)
    {
      const float* opr = opw + d*128;
      float acc[8] = {0,0,0,0,0,0,0,0};
      #pragma unroll
      for (int k4 = 0; k4 < 32; k4++) {
        float4 o4 = *(const float4*)&opr[k4*4];
        acc[k4 >> 2] += dot4(o4, *(const float4*)&vecB[k4*4]);
      }
      #pragma unroll
      for (int h = 0; h < 8; h++) OMw[om_off(d, h*20 + t)] = f2b(acc[h]);
    }
  } else {
    float suu = mean128(uh*uh, red);
    float sww = mean128(wh*wh, red);
    float suw = mean128(uh*wh, red);
    if (d == 0) {
      float* sc = (float*)(ws + WS_SCAL);
      sc[0] = suu; sc[1] = sww; sc[2] = suw;
    }
    vecA[d] = uh * g; vecB[d] = wh * g; vecC[d] = tln_b[d];
    __syncthreads();
    const float* wkr = ipw + (128 + d)*128;
    const float* wvr = ipw + (256 + d)*128;
    float ku = 0, kw = 0, kc = 0, vu = 0, vw = 0, vc = 0;
    for (int k4 = 0; k4 < 32; k4++) {
      float4 a4 = *(const float4*)&vecA[k4*4];
      float4 b4 = *(const float4*)&vecB[k4*4];
      float4 c4 = *(const float4*)&vecC[k4*4];
      float4 kv = *(const float4*)&wkr[k4*4];
      float4 vv = *(const float4*)&wvr[k4*4];
      ku += dot4(kv, a4); kw += dot4(kv, b4); kc += dot4(kv, c4);
      vu += dot4(vv, a4); vw += dot4(vv, b4); vc += dot4(vv, c4);
    }
    kc += ipb[128 + d]; vc += ipb[256 + d];
    kuA[d] = ku; kwA[d] = kw; kcA[d] = kc;
    float* qnw = (float*)(ws + WS_QN);
    qnw[0*128 + d] = qn[0][d]; qnw[1*128 + d] = qn[1][d]; qnw[2*128 + d] = qn[2][d];
    __syncthreads();
    // repurpose vecA/B/C to hold vu/vw/vc (all proj reads are done)
    vecA[d] = vu; vecB[d] = vw; vecC[d] = vc;
    __syncthreads();
    if (d < 24) {
      int w = d / 8, h = d % 8;
      float su = 0, sw = 0, sc2 = 0;
      #pragma unroll
      for (int dl = 0; dl < 16; dl++) {
        float q = qmat[w][h*16 + dl];
        su  += q * kuA[h*16 + dl];
        sw  += q * kwA[h*16 + dl];
        sc2 += q * kcA[h*16 + dl];
      }
      float* o = (float*)(ws + WS_SU);
      o[ 0 + w*8 + h] = 0.25f * su;
      o[24 + w*8 + h] = 0.25f * sw;
      o[48 + w*8 + h] = 0.25f * sc2;
    }
    // OM columns 160..191 (fragment layout)
    {
      const float* opr = opw + d*128;
      float au[8] = {0,0,0,0,0,0,0,0};
      float aw[8] = {0,0,0,0,0,0,0,0};
      float ac = 0;
      #pragma unroll
      for (int k4 = 0; k4 < 32; k4++) {
        float4 o4 = *(const float4*)&opr[k4*4];
        au[k4 >> 2] += dot4(o4, *(const float4*)&vecA[k4*4]);
        aw[k4 >> 2] += dot4(o4, *(const float4*)&vecB[k4*4]);
        ac          += dot4(o4, *(const float4*)&vecC[k4*4]);
      }
      #pragma unroll
      for (int h = 0; h < 8; h++) {
        OMw[om_off(d, 160 + h)] = f2b(au[h]);
        OMw[om_off(d, 168 + h)] = f2b(aw[h]);
      }
      OMw[om_off(d, 176)] = f2b(ac + opb[d]);
      #pragma unroll
      for (int i = 177; i < 192; i++) OMw[om_off(d, i)] = 0;
    }
  }
}

// ---------------------------------------------------------------------------
// Main fused kernel: 16 batch elements per WG (M = 48 rows), 256 threads.
// LDS 32256 B; __launch_bounds__(256,4) (R2's measured best).
// Structure/arithmetic = R4 (proven). Only B-load addressing + prefetch new.
#define GE 16
#define MR 48
#define SMEM_SZ 32256

__global__ __launch_bounds__(256, 4) void k_main(
    const float* __restrict__ tl, const float* __restrict__ tr,
    const float* __restrict__ f1b, const float* __restrict__ f2b_,
    const float* __restrict__ pag, const float* __restrict__ pab,
    const float* __restrict__ pfg, const float* __restrict__ pfb,
    const float* __restrict__ hw, const float* __restrict__ hb,
    const char* __restrict__ ws, float* __restrict__ out)
{
  __shared__ __align__(16) char smem[SMEM_SZ];
  // region A
  unsigned short* Z  = (unsigned short*)(smem);          // 48x200 (P0-P3)
  unsigned short* X  = (unsigned short*)(smem);          // 48x136 (aliases Z, post-b4)
  float* Pp2  = (float*)(smem + 13056);                  // [48][4] float2
  float* msc2 = (float*)(smem + 14592);                  // [48] float2
  float* Op   = (float*)(smem + 14976);                  // [48][4] float2
  // region B
  float* xr   = (float*)(smem + 19200);                  // 16x20
  float* yr   = (float*)(smem + 20480);
  float* rsA  = (float*)(smem + 21760);
  float* Sbl  = (float*)(smem + 23040);                  // 480
  float* SulA = (float*)(smem + 24960);                  // 72 (Su,Sw,Sc)
  float* QNl  = (float*)(smem + 25248);                  // 3x128
  float* pagl = (float*)(smem + 26784);                  // 128
  float* pabl = (float*)(smem + 27296);                  // 128
  float* Pp   = (float*)(smem + 27808);                  // [48][4] float2
  float* mscA = (float*)(smem + 29344);                  // [48] float2
  unsigned short* h1 = (unsigned short*)(smem + 19200);  // 48x136 (P5/P6)

  const unsigned short* OMf = (const unsigned short*)(ws + WS_OM);
  const unsigned short* W1f = (const unsigned short*)(ws + WS_FC1);
  const unsigned short* W2f = (const unsigned short*)(ws + WS_FC2);
  const float* QNw  = (const float*)(ws + WS_QN);
  const float* SBw  = (const float*)(ws + WS_SB);
  const float* SUw  = (const float*)(ws + WS_SU);
  const float* SCAL = (const float*)(ws + WS_SCAL);
  const float* SUB  = (const float*)(ws + WS_SUB);
  const float* SWB  = (const float*)(ws + WS_SWB);
  const float* SBB  = (const float*)(ws + WS_SBB);

  const int tid  = threadIdx.x;
  const int wg   = blockIdx.x;
  const int lane = tid & 63;
  const int wv   = tid >> 6;
  const int c    = lane & 15;     // MFMA column-in-tile / A-row index
  const int g    = lane >> 4;     // MFMA k-slice / output row-group
  const int nb   = wv * 32;       // N-slice base for this wave

  // ---- P0: stage tables, init Z constant tail, load coords ----
  for (int i = tid; i < 480; i += 256) Sbl[i] = SBw[i];
  if (tid < 72) SulA[tid] = SUw[tid];
  for (int i = tid; i < 384; i += 256) QNl[i] = QNw[i];
  if (tid < 128) { pagl[tid] = pag[tid]; pabl[tid] = pab[tid]; }
  if (tid < 48) {
    unsigned short* Zr = Z + tid*200;
    Zr[176] = 0x3F80;                  // bf16 1.0
    #pragma unroll
    for (int i = 177; i < 192; i++) Zr[i] = 0;
  }
  if (tid < 160) {
    int half = tid / 80;               // 0 = left, 1 = right
    int i4   = tid % 80;
    const float* src = half ? tr : tl;
    float4 v = *(const float4*)(src + wg*(GE*20) + i4*4);
    int e  = i4 / 5;
    int j  = (i4 % 5) * 4;
    int t0 = half*10 + j/2;
    xr[e*20 + t0]     = v.x; yr[e*20 + t0]     = v.y;
    xr[e*20 + t0 + 1] = v.z; yr[e*20 + t0 + 1] = v.w;
  }
  __syncthreads();                                        // b1

  // ---- P1: rs_t = rsqrt(quadratic(x,y) + eps); xr,yr <- x*rs, y*rs ----
  {
    float suu = SCAL[0], sww = SCAL[1], suw = SCAL[2];
    for (int i = tid; i < GE*20; i += 256) {
      int t = i % 20;
      float x = xr[i], y = yr[i];
      float var = suu*x*x + sww*y*y + 2.0f*suw*x*y
                + 2.0f*SUB[t]*x + 2.0f*SWB[t]*y + SBB[t];
      float rv = rsqrtf(var + 1e-5f);
      rsA[i] = rv; xr[i] = x*rv; yr[i] = y*rv;
    }
  }
  __syncthreads();                                        // b2

  // ---- P2: scores + softmax + P,Q -> Z rows (bf16) ----
  if (tid < 128) {
    int e = tid >> 3, h = tid & 7;
    float xa[20], ya[20], ra[20];
    #pragma unroll
    for (int tb = 0; tb < 5; tb++) {
      float4 xv = *(const float4*)&xr[e*20 + tb*4];
      float4 yv = *(const float4*)&yr[e*20 + tb*4];
      float4 rv = *(const float4*)&rsA[e*20 + tb*4];
      xa[tb*4+0]=xv.x; xa[tb*4+1]=xv.y; xa[tb*4+2]=xv.z; xa[tb*4+3]=xv.w;
      ya[tb*4+0]=yv.x; ya[tb*4+1]=yv.y; ya[tb*4+2]=yv.z; ya[tb*4+3]=yv.w;
      ra[tb*4+0]=rv.x; ra[tb*4+1]=rv.y; ra[tb*4+2]=rv.z; ra[tb*4+3]=rv.w;
    }
    float s[3][20];
    #pragma unroll
    for (int w = 0; w < 3; w++) {
      float suv = SulA[w*8 + h], swv = SulA[24 + w*8 + h], scv = SulA[48 + w*8 + h];
      const float* sb = &Sbl[(w*8 + h)*20];
      #pragma unroll
      for (int tb = 0; tb < 5; tb++) {
        float4 s4 = *(const float4*)&sb[tb*4];
        s[w][tb*4+0] = fmaf(xa[tb*4+0],suv, fmaf(ya[tb*4+0],swv, fmaf(ra[tb*4+0],s4.x, scv)));
        s[w][tb*4+1] = fmaf(xa[tb*4+1],suv, fmaf(ya[tb*4+1],swv, fmaf(ra[tb*4+1],s4.y, scv)));
        s[w][tb*4+2] = fmaf(xa[tb*4+2],suv, fmaf(ya[tb*4+2],swv, fmaf(ra[tb*4+2],s4.z, scv)));
        s[w][tb*4+3] = fmaf(xa[tb*4+3],suv, fmaf(ya[tb*4+3],swv, fmaf(ra[tb*4+3],s4.w, scv)));
      }
    }
    unsigned short* Zr0 = Z + e*3*200;
    #pragma unroll
    for (int w = 0; w < 3; w++) {
      float m = s[w][0];
      #pragma unroll
      for (int t2 = 1; t2 < 20; t2++) m = fmaxf(m, s[w][t2]);
      float sum = 0;
      #pragma unroll
      for (int t2 = 0; t2 < 20; t2++) { float p = __expf(s[w][t2] - m); s[w][t2] = p; sum += p; }
      float inv = 1.0f / sum;
      float P = 0, Q = 0;
      #pragma unroll
      for (int t2 = 0; t2 < 20; t2++) { P = fmaf(s[w][t2], xa[t2], P); Q = fmaf(s[w][t2], ya[t2], Q); }
      P *= inv; Q *= inv;
      unsigned short* Zr = Zr0 + w*200;
      #pragma unroll
      for (int t2 = 0; t2 < 10; t2++) {
        unsigned int lo = f2b(s[w][2*t2]   * ra[2*t2]   * inv);
        unsigned int hi = f2b(s[w][2*t2+1] * ra[2*t2+1] * inv);
        *(unsigned int*)&Zr[h*20 + 2*t2] = lo | (hi << 16);
      }
      Zr[160 + h] = f2b(P);
      Zr[168 + h] = f2b(Q);
    }
  }
  // Prefetch OM fragments (no Z dependency -> in flight across b3)
  bf16x8 BfOM[2][6];
  #pragma unroll
  for (int nt = 0; nt < 2; nt++)
    #pragma unroll
    for (int kt = 0; kt < 6; kt++)
      BfOM[nt][kt] = *(const bf16x8*)(OMf + ((wv*2 + nt)*6 + kt)*512 + lane*8);
  __syncthreads();                                        // b3

  // ---- P3: GEMM1 attn_out = Z(48x192) @ OM^T, fused LN -> X bf16 ----
  {
    f32x4 acc[3][2];
    #pragma unroll
    for (int mt = 0; mt < 3; mt++)
      #pragma unroll
      for (int nt = 0; nt < 2; nt++) acc[mt][nt] = (f32x4){0.f,0.f,0.f,0.f};
    #pragma unroll
    for (int kt = 0; kt < 6; kt++) {
      bf16x8 Af[3];
      #pragma unroll
      for (int mt = 0; mt < 3; mt++)
        Af[mt] = *(const bf16x8*)(Z + (mt*16 + c)*200 + kt*32 + g*8);
      #pragma unroll
      for (int mt = 0; mt < 3; mt++)
        #pragma unroll
        for (int nt = 0; nt < 2; nt++)
          acc[mt][nt] = mfma16(Af[mt], BfOM[nt][kt], acc[mt][nt]);
    }
    // fragment-LN: add queries_n, column-group reduce for mean/var
    float p1[3][4], p2[3][4];
    #pragma unroll
    for (int mt = 0; mt < 3; mt++)
      #pragma unroll
      for (int j = 0; j < 4; j++) {
        int row = mt*16 + g*4 + j;
        int w = row % 3;
        float v0 = acc[mt][0][j] + QNl[w*128 + nb + c];
        float v1 = acc[mt][1][j] + QNl[w*128 + nb + 16 + c];
        acc[mt][0][j] = v0; acc[mt][1][j] = v1;
        p1[mt][j] = v0 + v1;
        p2[mt][j] = v0*v0 + v1*v1;
      }
    #pragma unroll
    for (int mt = 0; mt < 3; mt++)
      #pragma unroll
      for (int j = 0; j < 4; j++) {
        #pragma unroll
        for (int mk = 1; mk <= 8; mk <<= 1) {
          p1[mt][j] += __shfl_xor(p1[mt][j], mk, 64);
          p2[mt][j] += __shfl_xor(p2[mt][j], mk, 64);
        }
      }
    if (c < 4) {
      #pragma unroll
      for (int mt = 0; mt < 3; mt++) {
        float a = (c==0)?p1[mt][0]:(c==1)?p1[mt][1]:(c==2)?p1[mt][2]:p1[mt][3];
        float b = (c==0)?p2[mt][0]:(c==1)?p2[mt][1]:(c==2)?p2[mt][2]:p2[mt][3];
        int row = mt*16 + g*4 + c;
        *(float2*)&Pp[row*8 + wv*2] = make_float2(a, b);
      }
    }
    __syncthreads();                                      // b4 (also: all Z reads done)
    if (tid < 192) {
      int row = tid >> 2, q = tid & 3;
      float2 pp = *(const float2*)&Pp[row*8 + q*2];
      float s1v = pp.x, s2v = pp.y;
      s1v += __shfl_xor(s1v, 1, 64); s1v += __shfl_xor(s1v, 2, 64);
      s2v += __shfl_xor(s2v, 1, 64); s2v += __shfl_xor(s2v, 2, 64);
      if (q == 0) {
        float m = s1v * (1.0f/128.0f);
        float var = s2v * (1.0f/128.0f) - m*m;
        *(float2*)&mscA[row*2] = make_float2(m, rsqrtf(var + 1e-5f));
      }
    }
    __syncthreads();                                      // b5
    // X = LN'd x, written straight from fragments (X aliases dead Z)
    {
      float pg0 = pagl[nb + c],      pb0 = pabl[nb + c];
      float pg1 = pagl[nb + 16 + c], pb1 = pabl[nb + 16 + c];
      #pragma unroll
      for (int mt = 0; mt < 3; mt++)
        #pragma unroll
        for (int j = 0; j < 4; j++) {
          int row = mt*16 + g*4 + j;
          float2 ms = *(const float2*)&mscA[row*2];
          X[row*136 + nb + c]      = f2b((acc[mt][0][j] - ms.x)*ms.y*pg0 + pb0);
          X[row*136 + nb + 16 + c] = f2b((acc[mt][1][j] - ms.x)*ms.y*pg1 + pb1);
        }
    }
  }
  // Prefetch W1 half 0 (no dependency -> in flight across b6)
  bf16x8 BfW1[2][4];
  #pragma unroll
  for (int nt = 0; nt < 2; nt++)
    #pragma unroll
    for (int kt = 0; kt < 4; kt++)
      BfW1[nt][kt] = *(const bf16x8*)(W1f + ((wv*2 + nt)*4 + kt)*512 + lane*8);
  __syncthreads();                                        // b6

  // ---- P5/P6: FFN in two K=128 halves sharing h1 (48x136 bf16) ----
  f32x4 acc2[3][2];
  #pragma unroll
  for (int mt = 0; mt < 3; mt++)
    #pragma unroll
    for (int nt = 0; nt < 2; nt++) acc2[mt][nt] = (f32x4){0.f,0.f,0.f,0.f};

  #pragma unroll
  for (int h = 0; h < 2; h++) {
    // P5: fc1 half -> relu -> h1 (BfW1 prefetched)
    {
      f32x4 acc[3][2];
      #pragma unroll
      for (int mt = 0; mt < 3; mt++)
        #pragma unroll
        for (int nt = 0; nt < 2; nt++) acc[mt][nt] = (f32x4){0.f,0.f,0.f,0.f};
      #pragma unroll
      for (int kt = 0; kt < 4; kt++) {
        bf16x8 Af[3];
        #pragma unroll
        for (int mt = 0; mt < 3; mt++)
          Af[mt] = *(const bf16x8*)(X + (mt*16 + c)*136 + kt*32 + g*8);
        #pragma unroll
        for (int mt = 0; mt < 3; mt++)
          #pragma unroll
          for (int nt = 0; nt < 2; nt++)
            acc[mt][nt] = mfma16(Af[mt], BfW1[nt][kt], acc[mt][nt]);
      }
      float bb0 = f1b[h*128 + nb + c];
      float bb1 = f1b[h*128 + nb + 16 + c];
      #pragma unroll
      for (int mt = 0; mt < 3; mt++)
        #pragma unroll
        for (int j = 0; j < 4; j++) {
          int row = mt*16 + g*4 + j;
          h1[row*136 + nb + c]      = f2b(fmaxf(acc[mt][0][j] + bb0, 0.0f));
          h1[row*136 + nb + 16 + c] = f2b(fmaxf(acc[mt][1][j] + bb1, 0.0f));
        }
    }
    // Prefetch W2 for this half (in flight across the h1-ready barrier)
    bf16x8 BfW2[2][4];
    #pragma unroll
    for (int nt = 0; nt < 2; nt++)
      #pragma unroll
      for (int kt = 0; kt < 4; kt++)
        BfW2[nt][kt] = *(const bf16x8*)(W2f + ((wv*2 + nt)*8 + h*4 + kt)*512 + lane*8);
    __syncthreads();                                      // b7 / b9: h1 ready
    // P6: fc2 partial over this K-half, accumulate into acc2
    #pragma unroll
    for (int kt = 0; kt < 4; kt++) {
      bf16x8 Af[3];
      #pragma unroll
      for (int mt = 0; mt < 3; mt++)
        Af[mt] = *(const bf16x8*)(h1 + (mt*16 + c)*136 + kt*32 + g*8);
      #pragma unroll
      for (int mt = 0; mt < 3; mt++)
        #pragma unroll
        for (int nt = 0; nt < 2; nt++)
          acc2[mt][nt] = mfma16(Af[mt], BfW2[nt][kt], acc2[mt][nt]);
    }
    if (h == 0) {
      // Prefetch W1 half 1 (in flight across the h1-rewrite barrier)
      #pragma unroll
      for (int nt = 0; nt < 2; nt++)
        #pragma unroll
        for (int kt = 0; kt < 4; kt++)
          BfW1[nt][kt] = *(const bf16x8*)(W1f + ((8 + wv*2 + nt)*4 + kt)*512 + lane*8);
      __syncthreads();                                    // b8 (h1 rewrite guard)
    }
  }

  // ---- P6b epilogue: h2+bias+residual -> fragment-LN -> head -> out ----
  {
    float bb0 = f2b_[nb + c];
    float bb1 = f2b_[nb + 16 + c];
    float p1[3][4], p2[3][4];
    #pragma unroll
    for (int mt = 0; mt < 3; mt++)
      #pragma unroll
      for (int j = 0; j < 4; j++) {
        int row = mt*16 + g*4 + j;
        float v0 = acc2[mt][0][j] + bb0 + b2f(X[row*136 + nb + c]);
        float v1 = acc2[mt][1][j] + bb1 + b2f(X[row*136 + nb + 16 + c]);
        acc2[mt][0][j] = v0; acc2[mt][1][j] = v1;
        p1[mt][j] = v0 + v1;
        p2[mt][j] = v0*v0 + v1*v1;
      }
    #pragma unroll
    for (int mt = 0; mt < 3; mt++)
      #pragma unroll
      for (int j = 0; j < 4; j++) {
        #pragma unroll
        for (int mk = 1; mk <= 8; mk <<= 1) {
          p1[mt][j] += __shfl_xor(p1[mt][j], mk, 64);
          p2[mt][j] += __shfl_xor(p2[mt][j], mk, 64);
        }
      }
    if (c < 4) {
      #pragma unroll
      for (int mt = 0; mt < 3; mt++) {
        float a = (c==0)?p1[mt][0]:(c==1)?p1[mt][1]:(c==2)?p1[mt][2]:p1[mt][3];
        float b = (c==0)?p2[mt][0]:(c==1)?p2[mt][1]:(c==2)?p2[mt][2]:p2[mt][3];
        int row = mt*16 + g*4 + c;
        *(float2*)&Pp2[row*8 + wv*2] = make_float2(a, b);
      }
    }
    __syncthreads();                                      // b10
    if (tid < 192) {
      int row = tid >> 2, q = tid & 3;
      float2 pp = *(const float2*)&Pp2[row*8 + q*2];
      float s1v = pp.x, s2v = pp.y;
      s1v += __shfl_xor(s1v, 1, 64); s1v += __shfl_xor(s1v, 2, 64);
      s2v += __shfl_xor(s2v, 1, 64); s2v += __shfl_xor(s2v, 2, 64);
      if (q == 0) {
        float m = s1v * (1.0f/128.0f);
        float var = s2v * (1.0f/128.0f) - m*m;
        *(float2*)&msc2[row*2] = make_float2(m, rsqrtf(var + 1e-5f));
      }
    }
    __syncthreads();                                      // b11
    {
      float fg0 = pfg[nb + c],        fb0 = pfb[nb + c];
      float fg1 = pfg[nb + 16 + c],   fb1 = pfb[nb + 16 + c];
      float hw00 = hw[nb + c],        hw01 = hw[nb + 16 + c];
      float hw10 = hw[128 + nb + c],  hw11 = hw[128 + nb + 16 + c];
      float o0[3][4], o1[3][4];
      #pragma unroll
      for (int mt = 0; mt < 3; mt++)
        #pragma unroll
        for (int j = 0; j < 4; j++) {
          int row = mt*16 + g*4 + j;
          float2 ms = *(const float2*)&msc2[row*2];
          float x0 = (acc2[mt][0][j] - ms.x)*ms.y*fg0 + fb0;
          float x1 = (acc2[mt][1][j] - ms.x)*ms.y*fg1 + fb1;
          o0[mt][j] = x0*hw00 + x1*hw01;
          o1[mt][j] = x0*hw10 + x1*hw11;
        }
      #pragma unroll
      for (int mt = 0; mt < 3; mt++)
        #pragma unroll
        for (int j = 0; j < 4; j++) {
          #pragma unroll
          for (int mk = 1; mk <= 8; mk <<= 1) {
            o0[mt][j] += __shfl_xor(o0[mt][j], mk, 64);
            o1[mt][j] += __shfl_xor(o1[mt][j], mk, 64);
          }
        }
      if (c < 4) {
        #pragma unroll
        for (int mt = 0; mt < 3; mt++) {
          float a = (c==0)?o0[mt][0]:(c==1)?o0[mt][1]:(c==2)?o0[mt][2]:o0[mt][3];
          float b = (c==0)?o1[mt][0]:(c==1)?o1[mt][1]:(c==2)?o1[mt][2]:o1[mt][3];
          int row = mt*16 + g*4 + c;
          *(float2*)&Op[row*8 + wv*2] = make_float2(a, b);
        }
      }
    }
    __syncthreads();                                      // b12
    if (tid < 48) {
      float4 a = *(const float4*)&Op[tid*8];
      float4 b = *(const float4*)&Op[tid*8 + 4];
      out[(wg*48 + tid)*2]     = a.x + a.z + b.x + b.z + hb[0];
      out[(wg*48 + tid)*2 + 1] = a.y + a.w + b.y + b.w + hb[1];
    }
  }
}

// ---------------------------------------------------------------------------
extern "C" void kernel_launch(void* const* d_in, const int* in_sizes, int n_in,
                              void* d_out, int out_size, void* d_ws, size_t ws_size,
                              hipStream_t stream) {
  const float* tl       = (const float*)d_in[0];
  const float* tr       = (const float*)d_in[1];
  const float* coord_w  = (const float*)d_in[2];
  const float* coord_b  = (const float*)d_in[3];
  const float* pos_emb  = (const float*)d_in[4];
  const float* side_emb = (const float*)d_in[5];
  const float* query_emb= (const float*)d_in[6];
  const float* tln_g    = (const float*)d_in[7];
  const float* tln_b    = (const float*)d_in[8];
  const float* qln_g    = (const float*)d_in[9];
  const float* qln_b    = (const float*)d_in[10];
  const float* ipw      = (const float*)d_in[11];
  const float* ipb      = (const float*)d_in[12];
  const float* opw      = (const float*)d_in[13];
  const float* opb      = (const float*)d_in[14];
  const float* f1w      = (const float*)d_in[15];
  const float* f1b      = (const float*)d_in[16];
  const float* f2w      = (const float*)d_in[17];
  const float* f2b2     = (const float*)d_in[18];
  const float* pag      = (const float*)d_in[19];
  const float* pab      = (const float*)d_in[20];
  const float* pfg      = (const float*)d_in[21];
  const float* pfb      = (const float*)d_in[22];
  const float* hw       = (const float*)d_in[23];
  const float* hb       = (const float*)d_in[24];
  char* ws = (char*)d_ws;

  k_prep<<<53, 128, 0, stream>>>(coord_w, coord_b, pos_emb, side_emb, query_emb,
                                 tln_g, tln_b, qln_g, qln_b, ipw, ipb,
                                 opw, opb, f1w, f2w, ws);
  k_main<<<32768 / GE, 256, 0, stream>>>(tl, tr, f1b, f2b2, pag, pab, pfg, pfb,
                                         hw, hb, ws, (float*)d_out);
}

// Round 8
// 172.552 us; speedup vs baseline: 1.4154x; 1.0065x over previous
//
#include <hip/hip_runtime.h>
#include <hip/hip_bf16.h>

// ---------------------------------------------------------------------------
// TransformerPlanner: algebra-collapsed fused implementation.
//
// R8 changes vs R7 (k_main 64us, passed):
//  - P2 softmax spread over ALL 256 threads: waves 0-1 handle w=0,1;
//    waves 2-3 handle w=2. P1 and pre-scaled xr/yr/rsA kept EXACTLY as R7
//    (pure work redistribution; no formula change). Serial units 3 -> 2,
//    smaller live set (s[20] not s[3][20]).
//  - Per-thread m/sc recompute from Pp/Pp2 broadcast reads: removes the
//    mscA/msc2 phases and barriers b5+b11 (12 -> 10 barriers).
// Retained from R7: fragment-ordered OM/W1/W2 + cross-barrier prefetch,
// (256,4), 12->10 barrier structure otherwise identical, non-atomic epilogue.
// ---------------------------------------------------------------------------

typedef __bf16 bf16x8 __attribute__((ext_vector_type(8)));
typedef float  f32x4  __attribute__((ext_vector_type(4)));
static_assert(sizeof(bf16x8) == 16, "bf16x8 must be 16B");

__device__ __forceinline__ unsigned short f2b(float x) {
  __bf16 h = (__bf16)x;
  return __builtin_bit_cast(unsigned short, h);
}
__device__ __forceinline__ float b2f(unsigned short u) {
  return (float)__builtin_bit_cast(__bf16, u);
}
__device__ __forceinline__ float dot4(float4 a, float4 b) {
  return a.x*b.x + a.y*b.y + a.z*b.z + a.w*b.w;
}
__device__ __forceinline__ f32x4 mfma16(bf16x8 a, bf16x8 b, f32x4 c) {
  return __builtin_amdgcn_mfma_f32_16x16x32_bf16(a, b, c, 0, 0, 0);
}

// Fragment-order offsets (ushort index) for B matrices:
// lane l of a (ntile,ktile) block holds n = ntile*16 + (l&15),
// k = ktile*32 + (l>>4)*8 .. +8. Block = 64 lanes x 8 ushort = 512.
__device__ __forceinline__ int om_off(int n, int k) {   // 128x192, 6 ktiles
  return (((n >> 4)*6 + (k >> 5))*64 + ((k >> 3) & 3)*16 + (n & 15))*8 + (k & 7);
}
__device__ __forceinline__ int w1_off(int n, int k) {   // 256x128, 4 ktiles
  return (((n >> 4)*4 + (k >> 5))*64 + ((k >> 3) & 3)*16 + (n & 15))*8 + (k & 7);
}
__device__ __forceinline__ int w2_off(int n, int k) {   // 128x256, 8 ktiles
  return (((n >> 4)*8 + (k >> 5))*64 + ((k >> 3) & 3)*16 + (n & 15))*8 + (k & 7);
}

// ---- workspace layout (byte offsets into d_ws) ----
#define WS_OM    0          // ushort[24576]  OM fragments (8 ntile x 6 ktile)
#define WS_FC1   49152      // ushort[32768]  fc1 fragments (16 x 4)
#define WS_FC2   114688     // ushort[32768]  fc2 fragments (8 x 8)
#define WS_QN    192000     // float[3*128]  LN'd queries
#define WS_SB    193536     // float[480]    Sb[w][h][t]
#define WS_SU    195456     // float[72]     Su[24],Sw[24],Sc[24]
#define WS_SCAL  195744     // float[3]      Suu,Sww,Suw
#define WS_SUB   195756     // float[20]
#define WS_SWB   195836     // float[20]
#define WS_SBB   195916     // float[20]

// ---------------------------------------------------------------------------
__device__ float mean128(float v, volatile float* red) {
  #pragma unroll
  for (int o = 32; o; o >>= 1) v += __shfl_down(v, o, 64);
  __syncthreads();
  if ((threadIdx.x & 63) == 0) red[threadIdx.x >> 6] = v;
  __syncthreads();
  return (red[0] + red[1]) * (1.0f / 128.0f);
}

// Merged prep kernel: 53 blocks x 128 threads.
//  b in [0,20)  : token block t -- per-t stats, Sb row, OM cols h*20+t
//  b == 20      : misc block -- scalars, QN, Su tables, OM cols 160..191
//  b in [21,37) : fc1 bf16 fragment repack
//  b in [37,53) : fc2 bf16 fragment repack
__global__ void k_prep(
    const float* __restrict__ coord_w, const float* __restrict__ coord_b,
    const float* __restrict__ pos_emb, const float* __restrict__ side_emb,
    const float* __restrict__ query_emb,
    const float* __restrict__ tln_g, const float* __restrict__ tln_b,
    const float* __restrict__ qln_g, const float* __restrict__ qln_b,
    const float* __restrict__ ipw, const float* __restrict__ ipb,
    const float* __restrict__ opw, const float* __restrict__ opb,
    const float* __restrict__ f1w, const float* __restrict__ f2w,
    char* __restrict__ ws)
{
  const int b = blockIdx.x, tid = threadIdx.x;   // 128 threads
  if (b >= 21) {
    if (b < 37) {
      unsigned short* dst = (unsigned short*)(ws + WS_FC1);
      int i0 = (b - 21)*2048;
      #pragma unroll
      for (int j = 0; j < 16; j++) {
        int i = i0 + j*128 + tid;
        dst[w1_off(i >> 7, i & 127)] = f2b(f1w[i]);
      }
    } else {
      unsigned short* dst = (unsigned short*)(ws + WS_FC2);
      int i0 = (b - 37)*2048;
      #pragma unroll
      for (int j = 0; j < 16; j++) {
        int i = i0 + j*128 + tid;
        dst[w2_off(i >> 8, i & 255)] = f2b(f2w[i]);
      }
    }
    return;
  }

  __shared__ float red[2];
  __shared__ float qn[3][128];
  __shared__ float qmat[3][128];
  __shared__ float vecA[128];
  __shared__ float vecB[128];
  __shared__ float vecC[128];
  __shared__ float kuA[128];
  __shared__ float kwA[128];
  __shared__ float kcA[128];
  const int d = tid;
  const int t = b;                // 0..19 = token blocks, 20 = misc
  unsigned short* OMw = (unsigned short*)(ws + WS_OM);

  float u  = coord_w[d*2+0];
  float w2 = coord_w[d*2+1];
  float g  = tln_g[d];
  float mu = mean128(u,  red);
  float mw = mean128(w2, red);
  float uh = u - mu, wh = w2 - mw;

  // LN(query_emb)
  #pragma unroll
  for (int w = 0; w < 3; w++) {
    float qe = query_emb[w*128 + d];
    float m  = mean128(qe, red);
    float m2 = mean128(qe*qe, red);
    float var = m2 - m*m;
    qn[w][d] = (qe - m) * rsqrtf(var + 1e-5f) * qln_g[d] + qln_b[d];
  }
  __syncthreads();
  // q = qn @ wq^T + bq
  {
    const float* wqr = ipw + d*128;
    float a0 = 0, a1 = 0, a2 = 0;
    for (int k4 = 0; k4 < 32; k4++) {
      float4 wv4 = *(const float4*)&wqr[k4*4];
      a0 += dot4(wv4, *(const float4*)&qn[0][k4*4]);
      a1 += dot4(wv4, *(const float4*)&qn[1][k4*4]);
      a2 += dot4(wv4, *(const float4*)&qn[2][k4*4]);
    }
    float bq = ipb[d];
    qmat[0][d] = a0 + bq; qmat[1][d] = a1 + bq; qmat[2][d] = a2 + bq;
  }
  __syncthreads();

  if (t < 20) {
    float base = coord_b[d] + pos_emb[(t % 10)*128 + d] + side_emb[(t < 10 ? 0 : 1)*128 + d];
    float mb = mean128(base, red);
    float bh = base - mb;
    float sub = mean128(uh*bh, red);
    float swb = mean128(wh*bh, red);
    float sbb = mean128(bh*bh, red);
    if (d == 0) {
      ((float*)(ws + WS_SUB))[t] = sub;
      ((float*)(ws + WS_SWB))[t] = swb;
      ((float*)(ws + WS_SBB))[t] = sbb;
    }
    vecA[d] = bh * g;
    __syncthreads();
    const float* wkr = ipw + (128 + d)*128;
    const float* wvr = ipw + (256 + d)*128;
    float kb = 0, vb = 0;
    for (int k4 = 0; k4 < 32; k4++) {
      float4 a4 = *(const float4*)&vecA[k4*4];
      kb += dot4(*(const float4*)&wkr[k4*4], a4);
      vb += dot4(*(const float4*)&wvr[k4*4], a4);
    }
    kuA[d] = kb;
    vecB[d] = vb;
    __syncthreads();
    if (d < 24) {
      int w = d / 8, h = d % 8;
      float s = 0;
      #pragma unroll
      for (int dl = 0; dl < 16; dl++) s += qmat[w][h*16 + dl] * kuA[h*16 + dl];
      ((float*)(ws + WS_SB))[(w*8 + h)*20 + t] = 0.25f * s;
    }
    // OM columns h*20+t for every output row n = d (fragment layout)
    {
      const float* opr = opw + d*128;
      float acc[8] = {0,0,0,0,0,0,0,0};
      #pragma unroll
      for (int k4 = 0; k4 < 32; k4++) {
        float4 o4 = *(const float4*)&opr[k4*4];
        acc[k4 >> 2] += dot4(o4, *(const float4*)&vecB[k4*4]);
      }
      #pragma unroll
      for (int h = 0; h < 8; h++) OMw[om_off(d, h*20 + t)] = f2b(acc[h]);
    }
  } else {
    float suu = mean128(uh*uh, red);
    float sww = mean128(wh*wh, red);
    float suw = mean128(uh*wh, red);
    if (d == 0) {
      float* sc = (float*)(ws + WS_SCAL);
      sc[0] = suu; sc[1] = sww; sc[2] = suw;
    }
    vecA[d] = uh * g; vecB[d] = wh * g; vecC[d] = tln_b[d];
    __syncthreads();
    const float* wkr = ipw + (128 + d)*128;
    const float* wvr = ipw + (256 + d)*128;
    float ku = 0, kw = 0, kc = 0, vu = 0, vw = 0, vc = 0;
    for (int k4 = 0; k4 < 32; k4++) {
      float4 a4 = *(const float4*)&vecA[k4*4];
      float4 b4 = *(const float4*)&vecB[k4*4];
      float4 c4 = *(const float4*)&vecC[k4*4];
      float4 kv = *(const float4*)&wkr[k4*4];
      float4 vv = *(const float4*)&wvr[k4*4];
      ku += dot4(kv, a4); kw += dot4(kv, b4); kc += dot4(kv, c4);
      vu += dot4(vv, a4); vw += dot4(vv, b4); vc += dot4(vv, c4);
    }
    kc += ipb[128 + d]; vc += ipb[256 + d];
    kuA[d] = ku; kwA[d] = kw; kcA[d] = kc;
    float* qnw = (float*)(ws + WS_QN);
    qnw[0*128 + d] = qn[0][d]; qnw[1*128 + d] = qn[1][d]; qnw[2*128 + d] = qn[2][d];
    __syncthreads();
    // repurpose vecA/B/C to hold vu/vw/vc (all proj reads are done)
    vecA[d] = vu; vecB[d] = vw; vecC[d] = vc;
    __syncthreads();
    if (d < 24) {
      int w = d / 8, h = d % 8;
      float su = 0, sw = 0, sc2 = 0;
      #pragma unroll
      for (int dl = 0; dl < 16; dl++) {
        float q = qmat[w][h*16 + dl];
        su  += q * kuA[h*16 + dl];
        sw  += q * kwA[h*16 + dl];
        sc2 += q * kcA[h*16 + dl];
      }
      float* o = (float*)(ws + WS_SU);
      o[ 0 + w*8 + h] = 0.25f * su;
      o[24 + w*8 + h] = 0.25f * sw;
      o[48 + w*8 + h] = 0.25f * sc2;
    }
    // OM columns 160..191 (fragment layout)
    {
      const float* opr = opw + d*128;
      float au[8] = {0,0,0,0,0,0,0,0};
      float aw[8] = {0,0,0,0,0,0,0,0};
      float ac = 0;
      #pragma unroll
      for (int k4 = 0; k4 < 32; k4++) {
        float4 o4 = *(const float4*)&opr[k4*4];
        au[k4 >> 2] += dot4(o4, *(const float4*)&vecA[k4*4]);
        aw[k4 >> 2] += dot4(o4, *(const float4*)&vecB[k4*4]);
        ac          += dot4(o4, *(const float4*)&vecC[k4*4]);
      }
      #pragma unroll
      for (int h = 0; h < 8; h++) {
        OMw[om_off(d, 160 + h)] = f2b(au[h]);
        OMw[om_off(d, 168 + h)] = f2b(aw[h]);
      }
      OMw[om_off(d, 176)] = f2b(ac + opb[d]);
      #pragma unroll
      for (int i = 177; i < 192; i++) OMw[om_off(d, i)] = 0;
    }
  }
}

// ---------------------------------------------------------------------------
// Main fused kernel: 16 batch elements per WG (M = 48 rows), 256 threads.
// LDS 32256 B; __launch_bounds__(256,4). 10 barriers.
#define GE 16
#define MR 48
#define SMEM_SZ 32256

__global__ __launch_bounds__(256, 4) void k_main(
    const float* __restrict__ tl, const float* __restrict__ tr,
    const float* __restrict__ f1b, const float* __restrict__ f2b_,
    const float* __restrict__ pag, const float* __restrict__ pab,
    const float* __restrict__ pfg, const float* __restrict__ pfb,
    const float* __restrict__ hw, const float* __restrict__ hb,
    const char* __restrict__ ws, float* __restrict__ out)
{
  __shared__ __align__(16) char smem[SMEM_SZ];
  // region A
  unsigned short* Z  = (unsigned short*)(smem);          // 48x200 (P0-P3)
  unsigned short* X  = (unsigned short*)(smem);          // 48x136 (aliases Z, post-b4)
  float* Pp2  = (float*)(smem + 13056);                  // [48][4] float2
  float* Op   = (float*)(smem + 14976);                  // [48][4] float2
  // region B
  float* xr   = (float*)(smem + 19200);                  // 16x20
  float* yr   = (float*)(smem + 20480);
  float* rsA  = (float*)(smem + 21760);
  float* Sbl  = (float*)(smem + 23040);                  // 480
  float* SulA = (float*)(smem + 24960);                  // 72 (Su,Sw,Sc)
  float* QNl  = (float*)(smem + 25248);                  // 3x128
  float* pagl = (float*)(smem + 26784);                  // 128
  float* pabl = (float*)(smem + 27296);                  // 128
  float* Pp   = (float*)(smem + 27808);                  // [48][4] float2
  unsigned short* h1 = (unsigned short*)(smem + 19200);  // 48x136 (P5/P6)

  const unsigned short* OMf = (const unsigned short*)(ws + WS_OM);
  const unsigned short* W1f = (const unsigned short*)(ws + WS_FC1);
  const unsigned short* W2f = (const unsigned short*)(ws + WS_FC2);
  const float* QNw  = (const float*)(ws + WS_QN);
  const float* SBw  = (const float*)(ws + WS_SB);
  const float* SUw  = (const float*)(ws + WS_SU);
  const float* SCAL = (const float*)(ws + WS_SCAL);
  const float* SUB  = (const float*)(ws + WS_SUB);
  const float* SWB  = (const float*)(ws + WS_SWB);
  const float* SBB  = (const float*)(ws + WS_SBB);

  const int tid  = threadIdx.x;
  const int wg   = blockIdx.x;
  const int lane = tid & 63;
  const int wv   = tid >> 6;
  const int c    = lane & 15;     // MFMA column-in-tile / A-row index
  const int g    = lane >> 4;     // MFMA k-slice / output row-group
  const int nb   = wv * 32;       // N-slice base for this wave

  // ---- P0: stage tables, init Z constant tail, load coords ----
  for (int i = tid; i < 480; i += 256) Sbl[i] = SBw[i];
  if (tid < 72) SulA[tid] = SUw[tid];
  for (int i = tid; i < 384; i += 256) QNl[i] = QNw[i];
  if (tid < 128) { pagl[tid] = pag[tid]; pabl[tid] = pab[tid]; }
  if (tid < 48) {
    unsigned short* Zr = Z + tid*200;
    Zr[176] = 0x3F80;                  // bf16 1.0
    #pragma unroll
    for (int i = 177; i < 192; i++) Zr[i] = 0;
  }
  if (tid < 160) {
    int half = tid / 80;               // 0 = left, 1 = right
    int i4   = tid % 80;
    const float* src = half ? tr : tl;
    float4 v = *(const float4*)(src + wg*(GE*20) + i4*4);
    int e  = i4 / 5;
    int j  = (i4 % 5) * 4;
    int t0 = half*10 + j/2;
    xr[e*20 + t0]     = v.x; yr[e*20 + t0]     = v.y;
    xr[e*20 + t0 + 1] = v.z; yr[e*20 + t0 + 1] = v.w;
  }
  __syncthreads();                                        // b1

  // ---- P1: rs_t = rsqrt(quadratic(x,y) + eps); xr,yr <- x*rs, y*rs ----
  {
    float suu = SCAL[0], sww = SCAL[1], suw = SCAL[2];
    for (int i = tid; i < GE*20; i += 256) {
      int t = i % 20;
      float x = xr[i], y = yr[i];
      float var = suu*x*x + sww*y*y + 2.0f*suw*x*y
                + 2.0f*SUB[t]*x + 2.0f*SWB[t]*y + SBB[t];
      float rv = rsqrtf(var + 1e-5f);
      rsA[i] = rv; xr[i] = x*rv; yr[i] = y*rv;
    }
  }
  __syncthreads();                                        // b2

  // ---- P2: scores + softmax + P,Q -> Z rows (bf16), ALL 256 threads ----
  // waves 0-1: w = 0 then 1 for (e,h); waves 2-3: w = 2 only.
  // Inputs (xr/yr/rsA pre-scaled by P1) identical to R7's P2.
  {
    const int e = (tid & 127) >> 3;
    const int h = tid & 7;
    const int whalf = tid >> 7;
    float xa[20], ya[20], ra[20];
    #pragma unroll
    for (int tb = 0; tb < 5; tb++) {
      float4 xv = *(const float4*)&xr[e*20 + tb*4];
      float4 yv = *(const float4*)&yr[e*20 + tb*4];
      float4 rv = *(const float4*)&rsA[e*20 + tb*4];
      xa[tb*4+0]=xv.x; xa[tb*4+1]=xv.y; xa[tb*4+2]=xv.z; xa[tb*4+3]=xv.w;
      ya[tb*4+0]=yv.x; ya[tb*4+1]=yv.y; ya[tb*4+2]=yv.z; ya[tb*4+3]=yv.w;
      ra[tb*4+0]=rv.x; ra[tb*4+1]=rv.y; ra[tb*4+2]=rv.z; ra[tb*4+3]=rv.w;
    }
    const int nu = whalf ? 1 : 2;
    for (int it = 0; it < nu; it++) {
      const int w = whalf ? 2 : it;
      float suv = SulA[w*8 + h], swv = SulA[24 + w*8 + h], scv = SulA[48 + w*8 + h];
      const float* sb = &Sbl[(w*8 + h)*20];
      float s[20];
      #pragma unroll
      for (int tb = 0; tb < 5; tb++) {
        float4 s4 = *(const float4*)&sb[tb*4];
        s[tb*4+0] = fmaf(xa[tb*4+0],suv, fmaf(ya[tb*4+0],swv, fmaf(ra[tb*4+0],s4.x, scv)));
        s[tb*4+1] = fmaf(xa[tb*4+1],suv, fmaf(ya[tb*4+1],swv, fmaf(ra[tb*4+1],s4.y, scv)));
        s[tb*4+2] = fmaf(xa[tb*4+2],suv, fmaf(ya[tb*4+2],swv, fmaf(ra[tb*4+2],s4.z, scv)));
        s[tb*4+3] = fmaf(xa[tb*4+3],suv, fmaf(ya[tb*4+3],swv, fmaf(ra[tb*4+3],s4.w, scv)));
      }
      float m = s[0];
      #pragma unroll
      for (int t2 = 1; t2 < 20; t2++) m = fmaxf(m, s[t2]);
      float sum = 0;
      #pragma unroll
      for (int t2 = 0; t2 < 20; t2++) { float p = __expf(s[t2] - m); s[t2] = p; sum += p; }
      float inv = 1.0f / sum;
      float P = 0, Q = 0;
      #pragma unroll
      for (int t2 = 0; t2 < 20; t2++) { P = fmaf(s[t2], xa[t2], P); Q = fmaf(s[t2], ya[t2], Q); }
      P *= inv; Q *= inv;
      unsigned short* Zr = Z + (e*3 + w)*200;
      #pragma unroll
      for (int t2 = 0; t2 < 10; t2++) {
        unsigned int lo = f2b(s[2*t2]   * ra[2*t2]   * inv);
        unsigned int hi = f2b(s[2*t2+1] * ra[2*t2+1] * inv);
        *(unsigned int*)&Zr[h*20 + 2*t2] = lo | (hi << 16);
      }
      Zr[160 + h] = f2b(P);
      Zr[168 + h] = f2b(Q);
    }
  }
  // Prefetch OM fragments (no Z dependency -> in flight across b3)
  bf16x8 BfOM[2][6];
  #pragma unroll
  for (int nt = 0; nt < 2; nt++)
    #pragma unroll
    for (int kt = 0; kt < 6; kt++)
      BfOM[nt][kt] = *(const bf16x8*)(OMf + ((wv*2 + nt)*6 + kt)*512 + lane*8);
  __syncthreads();                                        // b3

  // ---- P3: GEMM1 attn_out = Z(48x192) @ OM^T, fused LN -> X bf16 ----
  {
    f32x4 acc[3][2];
    #pragma unroll
    for (int mt = 0; mt < 3; mt++)
      #pragma unroll
      for (int nt = 0; nt < 2; nt++) acc[mt][nt] = (f32x4){0.f,0.f,0.f,0.f};
    #pragma unroll
    for (int kt = 0; kt < 6; kt++) {
      bf16x8 Af[3];
      #pragma unroll
      for (int mt = 0; mt < 3; mt++)
        Af[mt] = *(const bf16x8*)(Z + (mt*16 + c)*200 + kt*32 + g*8);
      #pragma unroll
      for (int mt = 0; mt < 3; mt++)
        #pragma unroll
        for (int nt = 0; nt < 2; nt++)
          acc[mt][nt] = mfma16(Af[mt], BfOM[nt][kt], acc[mt][nt]);
    }
    // fragment-LN: add queries_n, column-group reduce for mean/var
    float p1[3][4], p2[3][4];
    #pragma unroll
    for (int mt = 0; mt < 3; mt++)
      #pragma unroll
      for (int j = 0; j < 4; j++) {
        int row = mt*16 + g*4 + j;
        int w = row % 3;
        float v0 = acc[mt][0][j] + QNl[w*128 + nb + c];
        float v1 = acc[mt][1][j] + QNl[w*128 + nb + 16 + c];
        acc[mt][0][j] = v0; acc[mt][1][j] = v1;
        p1[mt][j] = v0 + v1;
        p2[mt][j] = v0*v0 + v1*v1;
      }
    #pragma unroll
    for (int mt = 0; mt < 3; mt++)
      #pragma unroll
      for (int j = 0; j < 4; j++) {
        #pragma unroll
        for (int mk = 1; mk <= 8; mk <<= 1) {
          p1[mt][j] += __shfl_xor(p1[mt][j], mk, 64);
          p2[mt][j] += __shfl_xor(p2[mt][j], mk, 64);
        }
      }
    if (c < 4) {
      #pragma unroll
      for (int mt = 0; mt < 3; mt++) {
        float a = (c==0)?p1[mt][0]:(c==1)?p1[mt][1]:(c==2)?p1[mt][2]:p1[mt][3];
        float b = (c==0)?p2[mt][0]:(c==1)?p2[mt][1]:(c==2)?p2[mt][2]:p2[mt][3];
        int row = mt*16 + g*4 + c;
        *(float2*)&Pp[row*8 + wv*2] = make_float2(a, b);
      }
    }
    __syncthreads();                                      // b4: Pp ready, Z dead
    // X = LN'd x; m/sc recomputed per thread from Pp (broadcast reads)
    {
      float pg0 = pagl[nb + c],      pb0 = pabl[nb + c];
      float pg1 = pagl[nb + 16 + c], pb1 = pabl[nb + 16 + c];
      #pragma unroll
      for (int mt = 0; mt < 3; mt++)
        #pragma unroll
        for (int j = 0; j < 4; j++) {
          int row = mt*16 + g*4 + j;
          float4 a = *(const float4*)&Pp[row*8];
          float4 b = *(const float4*)&Pp[row*8 + 4];
          float s1 = a.x + a.z + b.x + b.z;
          float s2 = a.y + a.w + b.y + b.w;
          float m  = s1 * (1.0f/128.0f);
          float sc = rsqrtf(s2 * (1.0f/128.0f) - m*m + 1e-5f);
          X[row*136 + nb + c]      = f2b((acc[mt][0][j] - m)*sc*pg0 + pb0);
          X[row*136 + nb + 16 + c] = f2b((acc[mt][1][j] - m)*sc*pg1 + pb1);
        }
    }
  }
  // Prefetch W1 half 0 (no dependency -> in flight across b5)
  bf16x8 BfW1[2][4];
  #pragma unroll
  for (int nt = 0; nt < 2; nt++)
    #pragma unroll
    for (int kt = 0; kt < 4; kt++)
      BfW1[nt][kt] = *(const bf16x8*)(W1f + ((wv*2 + nt)*4 + kt)*512 + lane*8);
  __syncthreads();                                        // b5: X ready

  // ---- P5/P6: FFN in two K=128 halves sharing h1 (48x136 bf16) ----
  f32x4 acc2[3][2];
  #pragma unroll
  for (int mt = 0; mt < 3; mt++)
    #pragma unroll
    for (int nt = 0; nt < 2; nt++) acc2[mt][nt] = (f32x4){0.f,0.f,0.f,0.f};

  #pragma unroll
  for (int h = 0; h < 2; h++) {
    // P5: fc1 half -> relu -> h1 (BfW1 prefetched)
    {
      f32x4 acc[3][2];
      #pragma unroll
      for (int mt = 0; mt < 3; mt++)
        #pragma unroll
        for (int nt = 0; nt < 2; nt++) acc[mt][nt] = (f32x4){0.f,0.f,0.f,0.f};
      #pragma unroll
      for (int kt = 0; kt < 4; kt++) {
        bf16x8 Af[3];
        #pragma unroll
        for (int mt = 0; mt < 3; mt++)
          Af[mt] = *(const bf16x8*)(X + (mt*16 + c)*136 + kt*32 + g*8);
        #pragma unroll
        for (int mt = 0; mt < 3; mt++)
          #pragma unroll
          for (int nt = 0; nt < 2; nt++)
            acc[mt][nt] = mfma16(Af[mt], BfW1[nt][kt], acc[mt][nt]);
      }
      float bb0 = f1b[h*128 + nb + c];
      float bb1 = f1b[h*128 + nb + 16 + c];
      #pragma unroll
      for (int mt = 0; mt < 3; mt++)
        #pragma unroll
        for (int j = 0; j < 4; j++) {
          int row = mt*16 + g*4 + j;
          h1[row*136 + nb + c]      = f2b(fmaxf(acc[mt][0][j] + bb0, 0.0f));
          h1[row*136 + nb + 16 + c] = f2b(fmaxf(acc[mt][1][j] + bb1, 0.0f));
        }
    }
    // Prefetch W2 for this half (in flight across the h1-ready barrier)
    bf16x8 BfW2[2][4];
    #pragma unroll
    for (int nt = 0; nt < 2; nt++)
      #pragma unroll
      for (int kt = 0; kt < 4; kt++)
        BfW2[nt][kt] = *(const bf16x8*)(W2f + ((wv*2 + nt)*8 + h*4 + kt)*512 + lane*8);
    __syncthreads();                                      // b6 / b8: h1 ready
    // P6: fc2 partial over this K-half, accumulate into acc2
    #pragma unroll
    for (int kt = 0; kt < 4; kt++) {
      bf16x8 Af[3];
      #pragma unroll
      for (int mt = 0; mt < 3; mt++)
        Af[mt] = *(const bf16x8*)(h1 + (mt*16 + c)*136 + kt*32 + g*8);
      #pragma unroll
      for (int mt = 0; mt < 3; mt++)
        #pragma unroll
        for (int nt = 0; nt < 2; nt++)
          acc2[mt][nt] = mfma16(Af[mt], BfW2[nt][kt], acc2[mt][nt]);
    }
    if (h == 0) {
      // Prefetch W1 half 1 (in flight across the h1-rewrite barrier)
      #pragma unroll
      for (int nt = 0; nt < 2; nt++)
        #pragma unroll
        for (int kt = 0; kt < 4; kt++)
          BfW1[nt][kt] = *(const bf16x8*)(W1f + ((8 + wv*2 + nt)*4 + kt)*512 + lane*8);
      __syncthreads();                                    // b7 (h1 rewrite guard)
    }
  }

  // ---- P6b epilogue: h2+bias+residual -> fragment-LN -> head -> out ----
  {
    float bb0 = f2b_[nb + c];
    float bb1 = f2b_[nb + 16 + c];
    float p1[3][4], p2[3][4];
    #pragma unroll
    for (int mt = 0; mt < 3; mt++)
      #pragma unroll
      for (int j = 0; j < 4; j++) {
        int row = mt*16 + g*4 + j;
        float v0 = acc2[mt][0][j] + bb0 + b2f(X[row*136 + nb + c]);
        float v1 = acc2[mt][1][j] + bb1 + b2f(X[row*136 + nb + 16 + c]);
        acc2[mt][0][j] = v0; acc2[mt][1][j] = v1;
        p1[mt][j] = v0 + v1;
        p2[mt][j] = v0*v0 + v1*v1;
      }
    #pragma unroll
    for (int mt = 0; mt < 3; mt++)
      #pragma unroll
      for (int j = 0; j < 4; j++) {
        #pragma unroll
        for (int mk = 1; mk <= 8; mk <<= 1) {
          p1[mt][j] += __shfl_xor(p1[mt][j], mk, 64);
          p2[mt][j] += __shfl_xor(p2[mt][j], mk, 64);
        }
      }
    if (c < 4) {
      #pragma unroll
      for (int mt = 0; mt < 3; mt++) {
        float a = (c==0)?p1[mt][0]:(c==1)?p1[mt][1]:(c==2)?p1[mt][2]:p1[mt][3];
        float b = (c==0)?p2[mt][0]:(c==1)?p2[mt][1]:(c==2)?p2[mt][2]:p2[mt][3];
        int row = mt*16 + g*4 + c;
        *(float2*)&Pp2[row*8 + wv*2] = make_float2(a, b);
      }
    }
    __syncthreads();                                      // b9: Pp2 ready
    // m/sc per thread from Pp2 (broadcast); head partials; cross-wave Op
    {
      float fg0 = pfg[nb + c],        fb0 = pfb[nb + c];
      float fg1 = pfg[nb + 16 + c],   fb1 = pfb[nb + 16 + c];
      float hw00 = hw[nb + c],        hw01 = hw[nb + 16 + c];
      float hw10 = hw[128 + nb + c],  hw11 = hw[128 + nb + 16 + c];
      float o0[3][4], o1[3][4];
      #pragma unroll
      for (int mt = 0; mt < 3; mt++)
        #pragma unroll
        for (int j = 0; j < 4; j++) {
          int row = mt*16 + g*4 + j;
          float4 a = *(const float4*)&Pp2[row*8];
          float4 b = *(const float4*)&Pp2[row*8 + 4];
          float s1 = a.x + a.z + b.x + b.z;
          float s2 = a.y + a.w + b.y + b.w;
          float m  = s1 * (1.0f/128.0f);
          float sc = rsqrtf(s2 * (1.0f/128.0f) - m*m + 1e-5f);
          float x0 = (acc2[mt][0][j] - m)*sc*fg0 + fb0;
          float x1 = (acc2[mt][1][j] - m)*sc*fg1 + fb1;
          o0[mt][j] = x0*hw00 + x1*hw01;
          o1[mt][j] = x0*hw10 + x1*hw11;
        }
      #pragma unroll
      for (int mt = 0; mt < 3; mt++)
        #pragma unroll
        for (int j = 0; j < 4; j++) {
          #pragma unroll
          for (int mk = 1; mk <= 8; mk <<= 1) {
            o0[mt][j] += __shfl_xor(o0[mt][j], mk, 64);
            o1[mt][j] += __shfl_xor(o1[mt][j], mk, 64);
          }
        }
      if (c < 4) {
        #pragma unroll
        for (int mt = 0; mt < 3; mt++) {
          float a = (c==0)?o0[mt][0]:(c==1)?o0[mt][1]:(c==2)?o0[mt][2]:o0[mt][3];
          float b = (c==0)?o1[mt][0]:(c==1)?o1[mt][1]:(c==2)?o1[mt][2]:o1[mt][3];
          int row = mt*16 + g*4 + c;
          *(float2*)&Op[row*8 + wv*2] = make_float2(a, b);
        }
      }
    }
    __syncthreads();                                      // b10: Op ready
    if (tid < 48) {
      float4 a = *(const float4*)&Op[tid*8];
      float4 b = *(const float4*)&Op[tid*8 + 4];
      out[(wg*48 + tid)*2]     = a.x + a.z + b.x + b.z + hb[0];
      out[(wg*48 + tid)*2 + 1] = a.y + a.w + b.y + b.w + hb[1];
    }
  }
}

// ---------------------------------------------------------------------------
extern "C" void kernel_launch(void* const* d_in, const int* in_sizes, int n_in,
                              void* d_out, int out_size, void* d_ws, size_t ws_size,
                              hipStream_t stream) {
  const float* tl       = (const float*)d_in[0];
  const float* tr       = (const float*)d_in[1];
  const float* coord_w  = (const float*)d_in[2];
  const float* coord_b  = (const float*)d_in[3];
  const float* pos_emb  = (const float*)d_in[4];
  const float* side_emb = (const float*)d_in[5];
  const float* query_emb= (const float*)d_in[6];
  const float* tln_g    = (const float*)d_in[7];
  const float* tln_b    = (const float*)d_in[8];
  const float* qln_g    = (const float*)d_in[9];
  const float* qln_b    = (const float*)d_in[10];
  const float* ipw      = (const float*)d_in[11];
  const float* ipb      = (const float*)d_in[12];
  const float* opw      = (const float*)d_in[13];
  const float* opb      = (const float*)d_in[14];
  const float* f1w      = (const float*)d_in[15];
  const float* f1b      = (const float*)d_in[16];
  const float* f2w      = (const float*)d_in[17];
  const float* f2b2     = (const float*)d_in[18];
  const float* pag      = (const float*)d_in[19];
  const float* pab      = (const float*)d_in[20];
  const float* pfg      = (const float*)d_in[21];
  const float* pfb      = (const float*)d_in[22];
  const float* hw       = (const float*)d_in[23];
  const float* hb       = (const float*)d_in[24];
  char* ws = (char*)d_ws;

  k_prep<<<53, 128, 0, stream>>>(coord_w, coord_b, pos_emb, side_emb, query_emb,
                                 tln_g, tln_b, qln_g, qln_b, ipw, ipb,
                                 opw, opb, f1w, f2w, ws);
  k_main<<<32768 / GE, 256, 0, stream>>>(tl, tr, f1b, f2b2, pag, pab, pfg, pfb,
                                         hw, hb, ws, (float*)d_out);
}